// Round 26
// baseline (118.479 us; speedup 1.0000x reference)
//
#include <hip/hip_runtime.h>
#include <hip/hip_bf16.h>

#define N_NODES 50000
#define N_EDGES 800000
#define IN_DIM  128
#define OUT_DIM 256
#define NBUCK   196        // ceil(50000/256) coarse buckets (256 nodes each)
#define BCAP    4608       // per-bucket edge capacity: mean 4096 + 8 sigma

typedef float f32x4 __attribute__((ext_vector_type(4)));
typedef _Float16 half8 __attribute__((ext_vector_type(8)));

__device__ __forceinline__ float silu_fast(float x) {
    return x * __builtin_amdgcn_rcpf(1.0f + __expf(-x));
}

// ======== frag-major layout (single fp16 plane) ========
// Operand X (row-major logical [R][K]) stored as 1KB chunks of half8:
//   chunk(tile, kt, lane l) = fp16[8] of X[tile*16 + (l&15)][kt*32 + (l>>4)*8 + j]
//   ushort offset = (tile*(K/32) + kt)*512 + l*8
// Layer-1 LDS operand additionally slot-swizzled: phys_slot = l ^ (kt<<1)
// (makes both the gather's direct stores and the MFMA reads bank-optimal).

// ---------------- bucketA: LDS counting sort -> coalesced bucket writes ---------
__global__ __launch_bounds__(256) void bucketA_kernel(
    const int* __restrict__ src, const int* __restrict__ dst,
    int* __restrict__ gCursD, int* __restrict__ gCursS,
    uint* __restrict__ pairsD, ushort* __restrict__ srcB, int E)
{
    __shared__ ushort sE[2048], dE[2048];      // 8 KB
    __shared__ uint   sortD[2048];             // 8 KB
    __shared__ ushort sortS[2048];             // 4 KB
    __shared__ int cntD[256], cntS[256];
    __shared__ int offD[256], offS[256];
    __shared__ int curD[256], curS[256];
    __shared__ int gBaseD[256], gBaseS[256];
    __shared__ int sd[256];

    const int tid = threadIdx.x;
    const int e0  = blockIdx.x * 2048;
    const int nE  = min(2048, E - e0);

    cntD[tid] = 0; cntS[tid] = 0;
    __syncthreads();
    #pragma unroll
    for (int q = 0; q < 8; ++q) {
        int i = q * 256 + tid;
        if (i < nE) {
            int s = src[e0 + i], d = dst[e0 + i];   // < 65536: fit ushort
            sE[i] = (ushort)s;
            dE[i] = (ushort)d;
            atomicAdd(&cntD[d >> 8], 1);
            atomicAdd(&cntS[s >> 8], 1);
        }
    }
    __syncthreads();

    int ownD = cntD[tid];
    sd[tid] = ownD;
    __syncthreads();
    #pragma unroll
    for (int off = 1; off < 256; off <<= 1) {
        int t = (tid >= off) ? sd[tid - off] : 0;
        __syncthreads();
        sd[tid] += t;
        __syncthreads();
    }
    offD[tid] = sd[tid] - ownD;
    __syncthreads();

    int ownS = cntS[tid];
    sd[tid] = ownS;
    __syncthreads();
    #pragma unroll
    for (int off = 1; off < 256; off <<= 1) {
        int t = (tid >= off) ? sd[tid - off] : 0;
        __syncthreads();
        sd[tid] += t;
        __syncthreads();
    }
    offS[tid] = sd[tid] - ownS;

    curD[tid] = offD[tid];
    curS[tid] = offS[tid];
    if (tid < NBUCK) {
        gBaseD[tid] = tid * BCAP + atomicAdd(&gCursD[tid], cntD[tid]);
        gBaseS[tid] = tid * BCAP + atomicAdd(&gCursS[tid], cntS[tid]);
    }
    __syncthreads();

    #pragma unroll
    for (int q = 0; q < 8; ++q) {
        int i = q * 256 + tid;
        if (i < nE) {
            int s = sE[i], d = dE[i];
            int slot  = atomicAdd(&curD[d >> 8], 1);
            sortD[slot] = ((uint)s << 16) | (uint)d;
            int slot2 = atomicAdd(&curS[s >> 8], 1);
            sortS[slot2] = (ushort)s;
        }
    }
    __syncthreads();

    #pragma unroll
    for (int q = 0; q < 8; ++q) {
        int i = q * 256 + tid;
        if (i < nE) {
            uint v = sortD[i];
            int s = (int)(v >> 16), d = (int)(v & 0xFFFFu);
            int b = d >> 8;
            int gpos = gBaseD[b] + (i - offD[b]);
            if (gpos < (b + 1) * BCAP)
                pairsD[gpos] = ((uint)s << 8) | (uint)(d & 255);
            int sv = sortS[i];
            int bs = sv >> 8;
            int gpos2 = gBaseS[bs] + (i - offS[bs]);
            if (gpos2 < (bs + 1) * BCAP)
                srcB[gpos2] = (ushort)(sv & 255);
        }
    }
}

// ---------------- bucketB: 3 roles in one grid (512 threads/block) --------------
// [0,196): per-bucket fine CSR -> edge_srcF (ushort src, node-sorted).
// [196,392): src histogram -> pre-scaled fp16 featsH for the bucket's nodes.
// [392,432): weight conversion -> frag-major single-plane fp16 Wfc/Wf1/Wf2.
__global__ __launch_bounds__(512) void bucketB_kernel(
    const uint* __restrict__ pairsD, const ushort* __restrict__ srcB,
    const int* __restrict__ gCursD, const int* __restrict__ gCursS,
    ushort* __restrict__ edge_srcF, int2* __restrict__ begcnt,
    const float* __restrict__ feats, _Float16* __restrict__ featsH,
    const float* __restrict__ Wc, const float* __restrict__ W1,
    const float* __restrict__ W2, ushort* __restrict__ Wfc,
    ushort* __restrict__ Wf1, ushort* __restrict__ Wf2)
{
    __shared__ uint pE[BCAP];                     // 18.4 KB
    __shared__ int h[256], sd[256], curs[256];
    __shared__ float scs[256];
    const int tid = threadIdx.x;

    if (blockIdx.x < NBUCK) {
        const int b = blockIdx.x;
        const int base = b * BCAP;
        const int cnt  = min(gCursD[b], BCAP);
        if (tid < 256) h[tid] = 0;
        __syncthreads();
        for (int i = tid; i < cnt; i += 512) {
            uint p = pairsD[base + i];
            pE[i] = p;
            atomicAdd(&h[p & 255], 1);
        }
        __syncthreads();
        int myc = (tid < 256) ? h[tid] : 0;
        if (tid < 256) sd[tid] = myc;
        __syncthreads();
        #pragma unroll
        for (int off = 1; off < 256; off <<= 1) {
            int t = (tid >= off && tid < 256) ? sd[tid - off] : 0;
            __syncthreads();
            if (tid < 256) sd[tid] += t;
            __syncthreads();
        }
        if (tid < 256) {
            int excl = sd[tid] - myc;
            int n = b * 256 + tid;
            if (n < N_NODES) begcnt[n] = make_int2(base + excl, myc);
            curs[tid] = excl;
        }
        __syncthreads();
        for (int i = tid; i < cnt; i += 512) {
            uint p = pE[i];
            int slot = atomicAdd(&curs[p & 255], 1);
            edge_srcF[base + slot] = (ushort)(p >> 8);
        }
    } else if (blockIdx.x < 2 * NBUCK) {
        const int b = blockIdx.x - NBUCK;
        const int base = b * BCAP;
        const int cntS = min(gCursS[b], BCAP);
        if (tid < 256) h[tid] = 0;
        __syncthreads();
        for (int i = tid; i < cntS; i += 512)
            atomicAdd(&h[srcB[base + i]], 1);
        __syncthreads();
        if (tid < 256) scs[tid] = rsqrtf(fmaxf((float)h[tid], 1.0f));
        __syncthreads();
        // convert this bucket's 256 nodes: 256 nodes x 16 half8-chunks
        #pragma unroll
        for (int it = 0; it < 8; ++it) {
            int idx = it * 512 + tid;          // (nl<<4)|c8
            int nl = idx >> 4, c8 = idx & 15;
            int n = b * 256 + nl;
            if (n < N_NODES) {
                float sc = scs[nl];
                const float* fp = feats + (size_t)n * IN_DIM + c8 * 8;
                float4 v0 = *reinterpret_cast<const float4*>(fp);
                float4 v1 = *reinterpret_cast<const float4*>(fp + 4);
                half8 hv;
                hv[0] = (_Float16)(v0.x * sc); hv[1] = (_Float16)(v0.y * sc);
                hv[2] = (_Float16)(v0.z * sc); hv[3] = (_Float16)(v0.w * sc);
                hv[4] = (_Float16)(v1.x * sc); hv[5] = (_Float16)(v1.y * sc);
                hv[6] = (_Float16)(v1.z * sc); hv[7] = (_Float16)(v1.w * sc);
                *reinterpret_cast<half8*>(&featsH[(size_t)n * IN_DIM + c8 * 8]) = hv;
            }
        }
    } else {
        int idx = (blockIdx.x - 2 * NBUCK) * 512 + tid;   // 40 blocks x 512 = 20480
        const float* W; ushort* Wf; int K, off;
        if (idx < 4096)        { W = Wc; Wf = Wfc; K = 128; off = idx; }
        else if (idx < 12288)  { W = W1; Wf = Wf1; K = 256; off = idx - 4096; }
        else if (idx < 20480)  { W = W2; Wf = Wf2; K = 256; off = idx - 12288; }
        else return;
        int NK = K / 32;
        int l = off & 63;
        int kt = (K == 128) ? ((off >> 6) & 3) : ((off >> 6) & 7);
        int ct = (K == 128) ? (off >> 8) : (off >> 9);
        int col = ct * 16 + (l & 15);
        int kb  = kt * 32 + (l >> 4) * 8;
        half8 hv;
        #pragma unroll
        for (int q = 0; q < 8; ++q)
            hv[q] = (_Float16)W[(size_t)(kb + q) * 256 + col];
        *reinterpret_cast<half8*>(Wf + ((size_t)(ct * NK + kt)) * 512 + l * 8) = hv;
    }
}

// ---------------- fully fused: fp16 gather (direct frag store) + fp16 MFMA MLP --
template <int NK>
__device__ __forceinline__ void mfma_loop(
    const ushort* __restrict__ a0, const ushort* __restrict__ a1,
    const ushort* __restrict__ w0, const ushort* __restrict__ w1,
    const ushort* __restrict__ w2, const ushort* __restrict__ w3,
    f32x4 acc[2][4])
{
    #pragma unroll
    for (int kt = 0; kt < NK; ++kt) {
        const int o = kt * 512;
        half8 ah[2], bw[4];
        ah[0] = *reinterpret_cast<const half8*>(a0 + o);
        ah[1] = *reinterpret_cast<const half8*>(a1 + o);
        bw[0] = *reinterpret_cast<const half8*>(w0 + o);
        bw[1] = *reinterpret_cast<const half8*>(w1 + o);
        bw[2] = *reinterpret_cast<const half8*>(w2 + o);
        bw[3] = *reinterpret_cast<const half8*>(w3 + o);
        #pragma unroll
        for (int m = 0; m < 2; ++m) {
            #pragma unroll
            for (int n = 0; n < 4; ++n) {
                acc[m][n] = __builtin_amdgcn_mfma_f32_16x16x32_f16(ah[m], bw[n], acc[m][n], 0, 0, 0);
            }
        }
    }
}

__global__ __launch_bounds__(256, 8) void fused_all_kernel(
    const _Float16* __restrict__ featsH, const ushort* __restrict__ edge_srcF,
    const int2* __restrict__ begcnt,
    const ushort* __restrict__ Wfc, const ushort* __restrict__ Wf1,
    const ushort* __restrict__ Wf2, const float* __restrict__ bc,
    const float* __restrict__ b1, const float* __restrict__ b2,
    float* __restrict__ out, int M)
{
    // ushorts [0,4096): layer-1 A operand (2 tiles x 4 kt chunks, slot-swizzled)
    // after layer 1:   [0,8192) = layer-2/3 A operand (2 tiles x 8 kt)
    __shared__ ushort fb[8192];   // exactly 16 KB -> 8 blocks/CU

    const int tid  = threadIdx.x;
    const int lane = tid & 63;
    const int wv   = tid >> 6;
    const int blk  = blockIdx.x;
    const int row0 = blk * 32;
    const int fr   = lane & 15;
    const int lg   = lane >> 4;
    const int fh   = fr >> 3;

    // ---- phase A: fp16 gather (pk_add tree) -> direct swizzled frag store ----
    {
        const int g   = tid >> 4;     // node-in-half 0..15
        const int l16 = tid & 15;     // owns cols l16*8 .. +7
        const int ktA = l16 >> 2;     // chunk within K=128
        const int seg = l16 & 3;      // 8-col segment within chunk
        #pragma unroll
        for (int p = 0; p < 2; ++p) {
            int nl = p * 16 + g;
            int n  = row0 + nl;
            f32x4 a0 = {0.f, 0.f, 0.f, 0.f}, a1 = {0.f, 0.f, 0.f, 0.f};
            if (n < M) {
                int2 bcn = begcnt[n];
                int j = bcn.x, jend = bcn.x + bcn.y;
                for (; j + 3 < jend; j += 4) {
                    int s0 = edge_srcF[j],     s1 = edge_srcF[j + 1];
                    int s2 = edge_srcF[j + 2], s3 = edge_srcF[j + 3];
                    half8 h0 = *reinterpret_cast<const half8*>(&featsH[(size_t)s0 * IN_DIM + l16 * 8]);
                    half8 h1 = *reinterpret_cast<const half8*>(&featsH[(size_t)s1 * IN_DIM + l16 * 8]);
                    half8 h2 = *reinterpret_cast<const half8*>(&featsH[(size_t)s2 * IN_DIM + l16 * 8]);
                    half8 h3 = *reinterpret_cast<const half8*>(&featsH[(size_t)s3 * IN_DIM + l16 * 8]);
                    half8 hs = (h0 + h1) + (h2 + h3);   // v_pk_add_f16, depth-2 chain
                    a0[0] += (float)hs[0]; a0[1] += (float)hs[1];
                    a0[2] += (float)hs[2]; a0[3] += (float)hs[3];
                    a1[0] += (float)hs[4]; a1[1] += (float)hs[5];
                    a1[2] += (float)hs[6]; a1[3] += (float)hs[7];
                }
                for (; j < jend; ++j) {
                    int s0 = edge_srcF[j];
                    half8 h0 = *reinterpret_cast<const half8*>(&featsH[(size_t)s0 * IN_DIM + l16 * 8]);
                    a0[0] += (float)h0[0]; a0[1] += (float)h0[1];
                    a0[2] += (float)h0[2]; a0[3] += (float)h0[3];
                    a1[0] += (float)h0[4]; a1[1] += (float)h0[5];
                    a1[2] += (float)h0[6]; a1[3] += (float)h0[7];
                }
                float di = rsqrtf(fmaxf((float)bcn.y, 1.0f));
                a0 = a0 * di;
                a1 = a1 * di;
            }
            // direct frag-major fp16 store, slot-swizzled: l' = l ^ (ktA<<1)
            half8 hv;
            #pragma unroll
            for (int q = 0; q < 4; ++q) { hv[q] = (_Float16)a0[q]; hv[4 + q] = (_Float16)a1[q]; }
            const int tile = nl >> 4;                       // == p
            const int l    = seg * 16 + (nl & 15);
            const int lsw_ = l ^ (ktA << 1);
            *reinterpret_cast<half8*>(fb + (tile * 4 + ktA) * 512 + lsw_ * 8) = hv;
        }
    }
    __syncthreads();

    // swizzled per-thread write base for layer-1/2 epilogues (single plane)
    ushort* fbase = fb + wv * 1024 + (lg << 5) + (fr & 7);
    const int lsw = (lane * 8) ^ ((lane >> 4) << 3);

    f32x4 acc[2][4];

    // ---- layer 1: K=128 (NK=4), A from fb (slot-swizzled per kt) ----
    {
        const ushort* w0 = Wfc + ((size_t)(wv * 4 + 0) * 4) * 512 + lane * 8;
        const ushort* w1 = Wfc + ((size_t)(wv * 4 + 1) * 4) * 512 + lane * 8;
        const ushort* w2 = Wfc + ((size_t)(wv * 4 + 2) * 4) * 512 + lane * 8;
        const ushort* w3 = Wfc + ((size_t)(wv * 4 + 3) * 4) * 512 + lane * 8;
        #pragma unroll
        for (int m = 0; m < 2; ++m)
            #pragma unroll
            for (int n = 0; n < 4; ++n) acc[m][n] = (f32x4)(0.f);
        const int la8 = lane * 8;
        __builtin_amdgcn_s_setprio(1);
        #pragma unroll
        for (int kt = 0; kt < 4; ++kt) {
            const int ao = kt * 512 + (la8 ^ (kt << 4));   // (lane ^ (kt<<1)) * 8
            const int wo = kt * 512;
            half8 ah[2], bw[4];
            ah[0] = *reinterpret_cast<const half8*>(fb + ao);
            ah[1] = *reinterpret_cast<const half8*>(fb + 2048 + ao);
            bw[0] = *reinterpret_cast<const half8*>(w0 + wo);
            bw[1] = *reinterpret_cast<const half8*>(w1 + wo);
            bw[2] = *reinterpret_cast<const half8*>(w2 + wo);
            bw[3] = *reinterpret_cast<const half8*>(w3 + wo);
            #pragma unroll
            for (int m = 0; m < 2; ++m)
                #pragma unroll
                for (int n = 0; n < 4; ++n)
                    acc[m][n] = __builtin_amdgcn_mfma_f32_16x16x32_f16(ah[m], bw[n], acc[m][n], 0, 0, 0);
        }
        __builtin_amdgcn_s_setprio(0);
    }
    __syncthreads();   // all layer-1 A reads done before epilogue overwrites

    // layer-1 epilogue: silu -> fp16 -> fb (swizzled direct, single plane)
    #pragma unroll
    for (int n = 0; n < 4; ++n) {
        float b = bc[wv * 64 + n * 16 + fr];
        const int kseg = 2 * (n & 1) + fh;
        const int noff = (n >> 1) * 512 + kseg * 128;
        #pragma unroll
        for (int m = 0; m < 2; ++m) {
            f32x4 v = acc[m][n];
            #pragma unroll
            for (int q = 0; q < 4; ++q) {
                _Float16 s = (_Float16)silu_fast(v[q] + b);
                fbase[m * 4096 + noff + (q ^ kseg) * 8] = __builtin_bit_cast(unsigned short, s);
            }
        }
    }
    __syncthreads();

    // ---- layer 2: K=256 (NK=8), A from fb (swizzled) ----
    {
        const ushort* a0 = fb + lsw;
        const ushort* a1 = fb + 4096 + lsw;
        const ushort* w0 = Wf1 + ((size_t)(wv * 4 + 0) * 8) * 512 + lane * 8;
        const ushort* w1 = Wf1 + ((size_t)(wv * 4 + 1) * 8) * 512 + lane * 8;
        const ushort* w2 = Wf1 + ((size_t)(wv * 4 + 2) * 8) * 512 + lane * 8;
        const ushort* w3 = Wf1 + ((size_t)(wv * 4 + 3) * 8) * 512 + lane * 8;
        #pragma unroll
        for (int m = 0; m < 2; ++m)
            #pragma unroll
            for (int n = 0; n < 4; ++n) acc[m][n] = (f32x4)(0.f);
        __builtin_amdgcn_s_setprio(1);
        mfma_loop<8>(a0, a1, w0, w1, w2, w3, acc);
        __builtin_amdgcn_s_setprio(0);
    }
    __syncthreads();   // all fb reads done before overwrite

    // layer-2 epilogue -> fb (swizzled direct, single plane)
    #pragma unroll
    for (int n = 0; n < 4; ++n) {
        float b = b1[wv * 64 + n * 16 + fr];
        const int kseg = 2 * (n & 1) + fh;
        const int noff = (n >> 1) * 512 + kseg * 128;
        #pragma unroll
        for (int m = 0; m < 2; ++m) {
            f32x4 v = acc[m][n];
            #pragma unroll
            for (int q = 0; q < 4; ++q) {
                _Float16 s = (_Float16)silu_fast(v[q] + b);
                fbase[m * 4096 + noff + (q ^ kseg) * 8] = __builtin_bit_cast(unsigned short, s);
            }
        }
    }
    __syncthreads();

    // ---- layer 3: K=256 (NK=8), A from fb (swizzled) ----
    {
        const ushort* a0 = fb + lsw;
        const ushort* a1 = fb + 4096 + lsw;
        const ushort* w0 = Wf2 + ((size_t)(wv * 4 + 0) * 8) * 512 + lane * 8;
        const ushort* w1 = Wf2 + ((size_t)(wv * 4 + 1) * 8) * 512 + lane * 8;
        const ushort* w2 = Wf2 + ((size_t)(wv * 4 + 2) * 8) * 512 + lane * 8;
        const ushort* w3 = Wf2 + ((size_t)(wv * 4 + 3) * 8) * 512 + lane * 8;
        #pragma unroll
        for (int m = 0; m < 2; ++m)
            #pragma unroll
            for (int n = 0; n < 4; ++n) acc[m][n] = (f32x4)(0.f);
        __builtin_amdgcn_s_setprio(1);
        mfma_loop<8>(a0, a1, w0, w1, w2, w3, acc);
        __builtin_amdgcn_s_setprio(0);
    }

    // layer-3 epilogue: direct f32 global stores (64B-contiguous per 16 lanes)
    #pragma unroll
    for (int n = 0; n < 4; ++n) {
        int col = wv * 64 + n * 16 + fr;
        float b = b2[col];
        #pragma unroll
        for (int m = 0; m < 2; ++m) {
            int rowb = row0 + m * 16 + lg * 4;
            f32x4 v = acc[m][n];
            #pragma unroll
            for (int q = 0; q < 4; ++q) {
                int row = rowb + q;
                if (row < M)
                    out[(size_t)row * OUT_DIM + col] = silu_fast(v[q] + b);
            }
        }
    }
}

extern "C" void kernel_launch(void* const* d_in, const int* in_sizes, int n_in,
                              void* d_out, int out_size, void* d_ws, size_t ws_size,
                              hipStream_t stream)
{
    const float* feats  = (const float*)d_in[0];
    const float* W_conv = (const float*)d_in[1];
    const float* b_conv = (const float*)d_in[2];
    const float* W1     = (const float*)d_in[3];
    const float* b1     = (const float*)d_in[4];
    const float* W2     = (const float*)d_in[5];
    const float* b2     = (const float*)d_in[6];
    const int*   src    = (const int*)d_in[7];
    const int*   dst    = (const int*)d_in[8];

    // workspace layout (bytes):
    //   [0, 784)                 gCursD (196 ints)
    //   [1024, 1808)             gCursS
    //   [4096, 404,096)          begcnt (50000 int2)
    //   [1,000,000, 4,612,672)   pairsD  (196 x 4608 uint)
    //   [4,612,672, 6,419,008)   srcB    (196 x 4608 ushort)
    //   [6,420,480, 8,226,816)   edge_srcF (196 x 4608 ushort, node-sorted CSR)
    //   [10,000,000, 22,800,000) featsH (50000 x 128 fp16, pre-scaled)
    //   [80,600,064, 80,665,600) Wfc (fp16 frag-major, 64KB)
    //   [80,665,600, 80,796,672) Wf1 (128KB)
    //   [80,796,672, 80,927,744) Wf2 (128KB)
    char* ws = (char*)d_ws;
    int*    gCursD    = (int*)(ws + 0);
    int*    gCursS    = (int*)(ws + 1024);
    int2*   begcnt    = (int2*)(ws + 4096);
    uint*   pairsD    = (uint*)(ws + 1000000);
    ushort* srcB      = (ushort*)(ws + 4612672);
    ushort* edge_srcF = (ushort*)(ws + 6420480);
    _Float16* featsH  = (_Float16*)(ws + 10000000);
    ushort* Wfc       = (ushort*)(ws + 80600064);
    ushort* Wf1       = (ushort*)(ws + 80665600);
    ushort* Wf2       = (ushort*)(ws + 80796672);

    hipMemsetAsync(ws, 0, 2048, stream);   // zero gCursD + gCursS

    const int ablocks = (N_EDGES + 2047) / 2048;   // 391
    bucketA_kernel<<<ablocks, 256, 0, stream>>>(src, dst, gCursD, gCursS, pairsD, srcB, N_EDGES);
    bucketB_kernel<<<NBUCK * 2 + 40, 512, 0, stream>>>(pairsD, srcB, gCursD, gCursS,
                                                       edge_srcF, begcnt,
                                                       feats, featsH,
                                                       W_conv, W1, W2, Wfc, Wf1, Wf2);

    const int gblocks = (N_NODES + 31) / 32;   // 1563
    fused_all_kernel<<<gblocks, 256, 0, stream>>>(featsH, edge_srcF, begcnt,
                                                  Wfc, Wf1, Wf2, b_conv, b1, b2,
                                                  (float*)d_out, N_NODES);
}

// Round 27
// 108.904 us; speedup vs baseline: 1.0879x; 1.0879x over previous
//
#include <hip/hip_runtime.h>
#include <hip/hip_bf16.h>

#define N_NODES 50000
#define N_EDGES 800000
#define IN_DIM  128
#define OUT_DIM 256
#define NBUCK   196        // ceil(50000/256) coarse buckets (256 nodes each)
#define BCAP    4608       // per-bucket edge capacity: mean 4096 + 8 sigma

typedef float f32x4 __attribute__((ext_vector_type(4)));
typedef _Float16 half8 __attribute__((ext_vector_type(8)));

__device__ __forceinline__ float silu_fast(float x) {
    return x * __builtin_amdgcn_rcpf(1.0f + __expf(-x));
}

// ======== frag-major layout (single fp16 plane) ========
// Operand X (row-major logical [R][K]) stored as 1KB chunks of half8:
//   chunk(tile, kt, lane l) = fp16[8] of X[tile*16 + (l&15)][kt*32 + (l>>4)*8 + j]
//   ushort offset = (tile*(K/32) + kt)*512 + l*8
// Layer-1 LDS operand additionally slot-swizzled: phys_slot = l ^ (kt<<1)
// (makes both the gather's direct stores and the MFMA reads bank-optimal).

// ---------------- bucketA: LDS counting sort -> coalesced bucket writes ---------
__global__ __launch_bounds__(256) void bucketA_kernel(
    const int* __restrict__ src, const int* __restrict__ dst,
    int* __restrict__ gCursD, int* __restrict__ gCursS,
    uint* __restrict__ pairsD, ushort* __restrict__ srcB, int E)
{
    __shared__ ushort sE[2048], dE[2048];      // 8 KB
    __shared__ uint   sortD[2048];             // 8 KB
    __shared__ ushort sortS[2048];             // 4 KB
    __shared__ int cntD[256], cntS[256];
    __shared__ int offD[256], offS[256];
    __shared__ int curD[256], curS[256];
    __shared__ int gBaseD[256], gBaseS[256];
    __shared__ int sd[256];

    const int tid = threadIdx.x;
    const int e0  = blockIdx.x * 2048;
    const int nE  = min(2048, E - e0);

    cntD[tid] = 0; cntS[tid] = 0;
    __syncthreads();
    #pragma unroll
    for (int q = 0; q < 8; ++q) {
        int i = q * 256 + tid;
        if (i < nE) {
            int s = src[e0 + i], d = dst[e0 + i];   // < 65536: fit ushort
            sE[i] = (ushort)s;
            dE[i] = (ushort)d;
            atomicAdd(&cntD[d >> 8], 1);
            atomicAdd(&cntS[s >> 8], 1);
        }
    }
    __syncthreads();

    int ownD = cntD[tid];
    sd[tid] = ownD;
    __syncthreads();
    #pragma unroll
    for (int off = 1; off < 256; off <<= 1) {
        int t = (tid >= off) ? sd[tid - off] : 0;
        __syncthreads();
        sd[tid] += t;
        __syncthreads();
    }
    offD[tid] = sd[tid] - ownD;
    __syncthreads();

    int ownS = cntS[tid];
    sd[tid] = ownS;
    __syncthreads();
    #pragma unroll
    for (int off = 1; off < 256; off <<= 1) {
        int t = (tid >= off) ? sd[tid - off] : 0;
        __syncthreads();
        sd[tid] += t;
        __syncthreads();
    }
    offS[tid] = sd[tid] - ownS;

    curD[tid] = offD[tid];
    curS[tid] = offS[tid];
    if (tid < NBUCK) {
        gBaseD[tid] = tid * BCAP + atomicAdd(&gCursD[tid], cntD[tid]);
        gBaseS[tid] = tid * BCAP + atomicAdd(&gCursS[tid], cntS[tid]);
    }
    __syncthreads();

    #pragma unroll
    for (int q = 0; q < 8; ++q) {
        int i = q * 256 + tid;
        if (i < nE) {
            int s = sE[i], d = dE[i];
            int slot  = atomicAdd(&curD[d >> 8], 1);
            sortD[slot] = ((uint)s << 16) | (uint)d;
            int slot2 = atomicAdd(&curS[s >> 8], 1);
            sortS[slot2] = (ushort)s;
        }
    }
    __syncthreads();

    #pragma unroll
    for (int q = 0; q < 8; ++q) {
        int i = q * 256 + tid;
        if (i < nE) {
            uint v = sortD[i];
            int s = (int)(v >> 16), d = (int)(v & 0xFFFFu);
            int b = d >> 8;
            int gpos = gBaseD[b] + (i - offD[b]);
            if (gpos < (b + 1) * BCAP)
                pairsD[gpos] = ((uint)s << 8) | (uint)(d & 255);
            int sv = sortS[i];
            int bs = sv >> 8;
            int gpos2 = gBaseS[bs] + (i - offS[bs]);
            if (gpos2 < (bs + 1) * BCAP)
                srcB[gpos2] = (ushort)(sv & 255);
        }
    }
}

// ---------------- bucketB: 3 roles in one grid (512 threads/block) --------------
// [0,196): per-bucket fine CSR -> edge_srcF (ushort src, node-sorted).
// [196,392): src histogram -> pre-scaled fp16 featsH for the bucket's nodes.
// [392,432): weight conversion -> frag-major single-plane fp16 Wfc/Wf1/Wf2.
__global__ __launch_bounds__(512) void bucketB_kernel(
    const uint* __restrict__ pairsD, const ushort* __restrict__ srcB,
    const int* __restrict__ gCursD, const int* __restrict__ gCursS,
    ushort* __restrict__ edge_srcF, int2* __restrict__ begcnt,
    const float* __restrict__ feats, _Float16* __restrict__ featsH,
    const float* __restrict__ Wc, const float* __restrict__ W1,
    const float* __restrict__ W2, ushort* __restrict__ Wfc,
    ushort* __restrict__ Wf1, ushort* __restrict__ Wf2)
{
    __shared__ uint pE[BCAP];                     // 18.4 KB
    __shared__ int h[256], sd[256], curs[256];
    __shared__ float scs[256];
    const int tid = threadIdx.x;

    if (blockIdx.x < NBUCK) {
        const int b = blockIdx.x;
        const int base = b * BCAP;
        const int cnt  = min(gCursD[b], BCAP);
        if (tid < 256) h[tid] = 0;
        __syncthreads();
        for (int i = tid; i < cnt; i += 512) {
            uint p = pairsD[base + i];
            pE[i] = p;
            atomicAdd(&h[p & 255], 1);
        }
        __syncthreads();
        int myc = (tid < 256) ? h[tid] : 0;
        if (tid < 256) sd[tid] = myc;
        __syncthreads();
        #pragma unroll
        for (int off = 1; off < 256; off <<= 1) {
            int t = (tid >= off && tid < 256) ? sd[tid - off] : 0;
            __syncthreads();
            if (tid < 256) sd[tid] += t;
            __syncthreads();
        }
        if (tid < 256) {
            int excl = sd[tid] - myc;
            int n = b * 256 + tid;
            if (n < N_NODES) begcnt[n] = make_int2(base + excl, myc);
            curs[tid] = excl;
        }
        __syncthreads();
        for (int i = tid; i < cnt; i += 512) {
            uint p = pE[i];
            int slot = atomicAdd(&curs[p & 255], 1);
            edge_srcF[base + slot] = (ushort)(p >> 8);
        }
    } else if (blockIdx.x < 2 * NBUCK) {
        const int b = blockIdx.x - NBUCK;
        const int base = b * BCAP;
        const int cntS = min(gCursS[b], BCAP);
        if (tid < 256) h[tid] = 0;
        __syncthreads();
        for (int i = tid; i < cntS; i += 512)
            atomicAdd(&h[srcB[base + i]], 1);
        __syncthreads();
        if (tid < 256) scs[tid] = rsqrtf(fmaxf((float)h[tid], 1.0f));
        __syncthreads();
        // convert this bucket's 256 nodes: 256 nodes x 16 half8-chunks
        #pragma unroll
        for (int it = 0; it < 8; ++it) {
            int idx = it * 512 + tid;          // (nl<<4)|c8
            int nl = idx >> 4, c8 = idx & 15;
            int n = b * 256 + nl;
            if (n < N_NODES) {
                float sc = scs[nl];
                const float* fp = feats + (size_t)n * IN_DIM + c8 * 8;
                float4 v0 = *reinterpret_cast<const float4*>(fp);
                float4 v1 = *reinterpret_cast<const float4*>(fp + 4);
                half8 hv;
                hv[0] = (_Float16)(v0.x * sc); hv[1] = (_Float16)(v0.y * sc);
                hv[2] = (_Float16)(v0.z * sc); hv[3] = (_Float16)(v0.w * sc);
                hv[4] = (_Float16)(v1.x * sc); hv[5] = (_Float16)(v1.y * sc);
                hv[6] = (_Float16)(v1.z * sc); hv[7] = (_Float16)(v1.w * sc);
                *reinterpret_cast<half8*>(&featsH[(size_t)n * IN_DIM + c8 * 8]) = hv;
            }
        }
    } else {
        int idx = (blockIdx.x - 2 * NBUCK) * 512 + tid;   // 40 blocks x 512 = 20480
        const float* W; ushort* Wf; int K, off;
        if (idx < 4096)        { W = Wc; Wf = Wfc; K = 128; off = idx; }
        else if (idx < 12288)  { W = W1; Wf = Wf1; K = 256; off = idx - 4096; }
        else if (idx < 20480)  { W = W2; Wf = Wf2; K = 256; off = idx - 12288; }
        else return;
        int NK = K / 32;
        int l = off & 63;
        int kt = (K == 128) ? ((off >> 6) & 3) : ((off >> 6) & 7);
        int ct = (K == 128) ? (off >> 8) : (off >> 9);
        int col = ct * 16 + (l & 15);
        int kb  = kt * 32 + (l >> 4) * 8;
        half8 hv;
        #pragma unroll
        for (int q = 0; q < 8; ++q)
            hv[q] = (_Float16)W[(size_t)(kb + q) * 256 + col];
        *reinterpret_cast<half8*>(Wf + ((size_t)(ct * NK + kt)) * 512 + l * 8) = hv;
    }
}

// ---------------- fully fused: fp16 gather (direct frag store) + fp16 MFMA MLP --
template <int NK>
__device__ __forceinline__ void mfma_loop(
    const ushort* __restrict__ a0, const ushort* __restrict__ a1,
    const ushort* __restrict__ w0, const ushort* __restrict__ w1,
    const ushort* __restrict__ w2, const ushort* __restrict__ w3,
    f32x4 acc[2][4])
{
    #pragma unroll
    for (int kt = 0; kt < NK; ++kt) {
        const int o = kt * 512;
        half8 ah[2], bw[4];
        ah[0] = *reinterpret_cast<const half8*>(a0 + o);
        ah[1] = *reinterpret_cast<const half8*>(a1 + o);
        bw[0] = *reinterpret_cast<const half8*>(w0 + o);
        bw[1] = *reinterpret_cast<const half8*>(w1 + o);
        bw[2] = *reinterpret_cast<const half8*>(w2 + o);
        bw[3] = *reinterpret_cast<const half8*>(w3 + o);
        #pragma unroll
        for (int m = 0; m < 2; ++m) {
            #pragma unroll
            for (int n = 0; n < 4; ++n) {
                acc[m][n] = __builtin_amdgcn_mfma_f32_16x16x32_f16(ah[m], bw[n], acc[m][n], 0, 0, 0);
            }
        }
    }
}

__global__ __launch_bounds__(256, 6) void fused_all_kernel(
    const _Float16* __restrict__ featsH, const ushort* __restrict__ edge_srcF,
    const int2* __restrict__ begcnt,
    const ushort* __restrict__ Wfc, const ushort* __restrict__ Wf1,
    const ushort* __restrict__ Wf2, const float* __restrict__ bc,
    const float* __restrict__ b1, const float* __restrict__ b2,
    float* __restrict__ out, int M)
{
    // ushorts [0,4096): layer-1 A operand (2 tiles x 4 kt chunks, slot-swizzled)
    // after layer 1:   [0,8192) = layer-2/3 A operand (2 tiles x 8 kt)
    __shared__ ushort fb[8192];   // exactly 16 KB

    const int tid  = threadIdx.x;
    const int lane = tid & 63;
    const int wv   = tid >> 6;
    const int blk  = blockIdx.x;
    const int row0 = blk * 32;
    const int fr   = lane & 15;
    const int lg   = lane >> 4;
    const int fh   = fr >> 3;

    // ---- phase A: fp16 gather (pk_add tree) -> direct swizzled frag store ----
    {
        const int g   = tid >> 4;     // node-in-half 0..15
        const int l16 = tid & 15;     // owns cols l16*8 .. +7
        const int ktA = l16 >> 2;     // chunk within K=128
        const int seg = l16 & 3;      // 8-col segment within chunk
        #pragma unroll
        for (int p = 0; p < 2; ++p) {
            int nl = p * 16 + g;
            int n  = row0 + nl;
            f32x4 a0 = {0.f, 0.f, 0.f, 0.f}, a1 = {0.f, 0.f, 0.f, 0.f};
            if (n < M) {
                int2 bcn = begcnt[n];
                int j = bcn.x, jend = bcn.x + bcn.y;
                for (; j + 3 < jend; j += 4) {
                    int s0 = edge_srcF[j],     s1 = edge_srcF[j + 1];
                    int s2 = edge_srcF[j + 2], s3 = edge_srcF[j + 3];
                    half8 h0 = *reinterpret_cast<const half8*>(&featsH[(size_t)s0 * IN_DIM + l16 * 8]);
                    half8 h1 = *reinterpret_cast<const half8*>(&featsH[(size_t)s1 * IN_DIM + l16 * 8]);
                    half8 h2 = *reinterpret_cast<const half8*>(&featsH[(size_t)s2 * IN_DIM + l16 * 8]);
                    half8 h3 = *reinterpret_cast<const half8*>(&featsH[(size_t)s3 * IN_DIM + l16 * 8]);
                    half8 hs = (h0 + h1) + (h2 + h3);   // v_pk_add_f16, depth-2 chain
                    a0[0] += (float)hs[0]; a0[1] += (float)hs[1];
                    a0[2] += (float)hs[2]; a0[3] += (float)hs[3];
                    a1[0] += (float)hs[4]; a1[1] += (float)hs[5];
                    a1[2] += (float)hs[6]; a1[3] += (float)hs[7];
                }
                for (; j < jend; ++j) {
                    int s0 = edge_srcF[j];
                    half8 h0 = *reinterpret_cast<const half8*>(&featsH[(size_t)s0 * IN_DIM + l16 * 8]);
                    a0[0] += (float)h0[0]; a0[1] += (float)h0[1];
                    a0[2] += (float)h0[2]; a0[3] += (float)h0[3];
                    a1[0] += (float)h0[4]; a1[1] += (float)h0[5];
                    a1[2] += (float)h0[6]; a1[3] += (float)h0[7];
                }
                float di = rsqrtf(fmaxf((float)bcn.y, 1.0f));
                a0 = a0 * di;
                a1 = a1 * di;
            }
            // direct frag-major fp16 store, slot-swizzled: l' = l ^ (ktA<<1)
            half8 hv;
            #pragma unroll
            for (int q = 0; q < 4; ++q) { hv[q] = (_Float16)a0[q]; hv[4 + q] = (_Float16)a1[q]; }
            const int tile = nl >> 4;                       // == p
            const int l    = seg * 16 + (nl & 15);
            const int lsw_ = l ^ (ktA << 1);
            *reinterpret_cast<half8*>(fb + (tile * 4 + ktA) * 512 + lsw_ * 8) = hv;
        }
    }
    __syncthreads();

    // swizzled per-thread write base for layer-1/2 epilogues (single plane)
    ushort* fbase = fb + wv * 1024 + (lg << 5) + (fr & 7);
    const int lsw = (lane * 8) ^ ((lane >> 4) << 3);

    f32x4 acc[2][4];

    // ---- layer 1: K=128 (NK=4), A from fb (slot-swizzled per kt) ----
    {
        const ushort* w0 = Wfc + ((size_t)(wv * 4 + 0) * 4) * 512 + lane * 8;
        const ushort* w1 = Wfc + ((size_t)(wv * 4 + 1) * 4) * 512 + lane * 8;
        const ushort* w2 = Wfc + ((size_t)(wv * 4 + 2) * 4) * 512 + lane * 8;
        const ushort* w3 = Wfc + ((size_t)(wv * 4 + 3) * 4) * 512 + lane * 8;
        #pragma unroll
        for (int m = 0; m < 2; ++m)
            #pragma unroll
            for (int n = 0; n < 4; ++n) acc[m][n] = (f32x4)(0.f);
        const int la8 = lane * 8;
        __builtin_amdgcn_s_setprio(1);
        #pragma unroll
        for (int kt = 0; kt < 4; ++kt) {
            const int ao = kt * 512 + (la8 ^ (kt << 4));   // (lane ^ (kt<<1)) * 8
            const int wo = kt * 512;
            half8 ah[2], bw[4];
            ah[0] = *reinterpret_cast<const half8*>(fb + ao);
            ah[1] = *reinterpret_cast<const half8*>(fb + 2048 + ao);
            bw[0] = *reinterpret_cast<const half8*>(w0 + wo);
            bw[1] = *reinterpret_cast<const half8*>(w1 + wo);
            bw[2] = *reinterpret_cast<const half8*>(w2 + wo);
            bw[3] = *reinterpret_cast<const half8*>(w3 + wo);
            #pragma unroll
            for (int m = 0; m < 2; ++m)
                #pragma unroll
                for (int n = 0; n < 4; ++n)
                    acc[m][n] = __builtin_amdgcn_mfma_f32_16x16x32_f16(ah[m], bw[n], acc[m][n], 0, 0, 0);
        }
        __builtin_amdgcn_s_setprio(0);
    }
    __syncthreads();   // all layer-1 A reads done before epilogue overwrites

    // layer-1 epilogue: silu -> fp16 -> fb (swizzled direct, single plane)
    #pragma unroll
    for (int n = 0; n < 4; ++n) {
        float b = bc[wv * 64 + n * 16 + fr];
        const int kseg = 2 * (n & 1) + fh;
        const int noff = (n >> 1) * 512 + kseg * 128;
        #pragma unroll
        for (int m = 0; m < 2; ++m) {
            f32x4 v = acc[m][n];
            #pragma unroll
            for (int q = 0; q < 4; ++q) {
                _Float16 s = (_Float16)silu_fast(v[q] + b);
                fbase[m * 4096 + noff + (q ^ kseg) * 8] = __builtin_bit_cast(unsigned short, s);
            }
        }
    }
    __syncthreads();

    // ---- layer 2: K=256 (NK=8), A from fb (swizzled) ----
    {
        const ushort* a0 = fb + lsw;
        const ushort* a1 = fb + 4096 + lsw;
        const ushort* w0 = Wf1 + ((size_t)(wv * 4 + 0) * 8) * 512 + lane * 8;
        const ushort* w1 = Wf1 + ((size_t)(wv * 4 + 1) * 8) * 512 + lane * 8;
        const ushort* w2 = Wf1 + ((size_t)(wv * 4 + 2) * 8) * 512 + lane * 8;
        const ushort* w3 = Wf1 + ((size_t)(wv * 4 + 3) * 8) * 512 + lane * 8;
        #pragma unroll
        for (int m = 0; m < 2; ++m)
            #pragma unroll
            for (int n = 0; n < 4; ++n) acc[m][n] = (f32x4)(0.f);
        __builtin_amdgcn_s_setprio(1);
        mfma_loop<8>(a0, a1, w0, w1, w2, w3, acc);
        __builtin_amdgcn_s_setprio(0);
    }
    __syncthreads();   // all fb reads done before overwrite

    // layer-2 epilogue -> fb (swizzled direct, single plane)
    #pragma unroll
    for (int n = 0; n < 4; ++n) {
        float b = b1[wv * 64 + n * 16 + fr];
        const int kseg = 2 * (n & 1) + fh;
        const int noff = (n >> 1) * 512 + kseg * 128;
        #pragma unroll
        for (int m = 0; m < 2; ++m) {
            f32x4 v = acc[m][n];
            #pragma unroll
            for (int q = 0; q < 4; ++q) {
                _Float16 s = (_Float16)silu_fast(v[q] + b);
                fbase[m * 4096 + noff + (q ^ kseg) * 8] = __builtin_bit_cast(unsigned short, s);
            }
        }
    }
    __syncthreads();

    // ---- layer 3: K=256 (NK=8), A from fb (swizzled) ----
    {
        const ushort* a0 = fb + lsw;
        const ushort* a1 = fb + 4096 + lsw;
        const ushort* w0 = Wf2 + ((size_t)(wv * 4 + 0) * 8) * 512 + lane * 8;
        const ushort* w1 = Wf2 + ((size_t)(wv * 4 + 1) * 8) * 512 + lane * 8;
        const ushort* w2 = Wf2 + ((size_t)(wv * 4 + 2) * 8) * 512 + lane * 8;
        const ushort* w3 = Wf2 + ((size_t)(wv * 4 + 3) * 8) * 512 + lane * 8;
        #pragma unroll
        for (int m = 0; m < 2; ++m)
            #pragma unroll
            for (int n = 0; n < 4; ++n) acc[m][n] = (f32x4)(0.f);
        __builtin_amdgcn_s_setprio(1);
        mfma_loop<8>(a0, a1, w0, w1, w2, w3, acc);
        __builtin_amdgcn_s_setprio(0);
    }

    // layer-3 epilogue: direct f32 global stores (64B-contiguous per 16 lanes)
    #pragma unroll
    for (int n = 0; n < 4; ++n) {
        int col = wv * 64 + n * 16 + fr;
        float b = b2[col];
        #pragma unroll
        for (int m = 0; m < 2; ++m) {
            int rowb = row0 + m * 16 + lg * 4;
            f32x4 v = acc[m][n];
            #pragma unroll
            for (int q = 0; q < 4; ++q) {
                int row = rowb + q;
                if (row < M)
                    out[(size_t)row * OUT_DIM + col] = silu_fast(v[q] + b);
            }
        }
    }
}

extern "C" void kernel_launch(void* const* d_in, const int* in_sizes, int n_in,
                              void* d_out, int out_size, void* d_ws, size_t ws_size,
                              hipStream_t stream)
{
    const float* feats  = (const float*)d_in[0];
    const float* W_conv = (const float*)d_in[1];
    const float* b_conv = (const float*)d_in[2];
    const float* W1     = (const float*)d_in[3];
    const float* b1     = (const float*)d_in[4];
    const float* W2     = (const float*)d_in[5];
    const float* b2     = (const float*)d_in[6];
    const int*   src    = (const int*)d_in[7];
    const int*   dst    = (const int*)d_in[8];

    // workspace layout (bytes):
    //   [0, 784)                 gCursD (196 ints)
    //   [1024, 1808)             gCursS
    //   [4096, 404,096)          begcnt (50000 int2)
    //   [1,000,000, 4,612,672)   pairsD  (196 x 4608 uint)
    //   [4,612,672, 6,419,008)   srcB    (196 x 4608 ushort)
    //   [6,420,480, 8,226,816)   edge_srcF (196 x 4608 ushort, node-sorted CSR)
    //   [10,000,000, 22,800,000) featsH (50000 x 128 fp16, pre-scaled)
    //   [80,600,064, 80,665,600) Wfc (fp16 frag-major, 64KB)
    //   [80,665,600, 80,796,672) Wf1 (128KB)
    //   [80,796,672, 80,927,744) Wf2 (128KB)
    char* ws = (char*)d_ws;
    int*    gCursD    = (int*)(ws + 0);
    int*    gCursS    = (int*)(ws + 1024);
    int2*   begcnt    = (int2*)(ws + 4096);
    uint*   pairsD    = (uint*)(ws + 1000000);
    ushort* srcB      = (ushort*)(ws + 4612672);
    ushort* edge_srcF = (ushort*)(ws + 6420480);
    _Float16* featsH  = (_Float16*)(ws + 10000000);
    ushort* Wfc       = (ushort*)(ws + 80600064);
    ushort* Wf1       = (ushort*)(ws + 80665600);
    ushort* Wf2       = (ushort*)(ws + 80796672);

    hipMemsetAsync(ws, 0, 2048, stream);   // zero gCursD + gCursS

    const int ablocks = (N_EDGES + 2047) / 2048;   // 391
    bucketA_kernel<<<ablocks, 256, 0, stream>>>(src, dst, gCursD, gCursS, pairsD, srcB, N_EDGES);
    bucketB_kernel<<<NBUCK * 2 + 40, 512, 0, stream>>>(pairsD, srcB, gCursD, gCursS,
                                                       edge_srcF, begcnt,
                                                       feats, featsH,
                                                       W_conv, W1, W2, Wfc, Wf1, Wf2);

    const int gblocks = (N_NODES + 31) / 32;   // 1563
    fused_all_kernel<<<gblocks, 256, 0, stream>>>(featsH, edge_srcF, begcnt,
                                                  Wfc, Wf1, Wf2, b_conv, b1, b2,
                                                  (float*)d_out, N_NODES);
}

// Round 28
// 106.202 us; speedup vs baseline: 1.1156x; 1.0254x over previous
//
#include <hip/hip_runtime.h>
#include <hip/hip_bf16.h>

#define N_NODES 50000
#define N_EDGES 800000
#define IN_DIM  128
#define OUT_DIM 256
#define NBUCK   196        // ceil(50000/256) coarse buckets (256 nodes each)
#define BCAP    4608       // per-bucket edge capacity: mean 4096 + 8 sigma

typedef float f32x4 __attribute__((ext_vector_type(4)));
typedef _Float16 half8 __attribute__((ext_vector_type(8)));

__device__ __forceinline__ float silu_fast(float x) {
    return x * __builtin_amdgcn_rcpf(1.0f + __expf(-x));
}

// ======== frag-major layout (single fp16 plane) ========
// Operand X (row-major logical [R][K]) stored as 1KB chunks of half8:
//   chunk(tile, kt, lane l) = fp16[8] of X[tile*16 + (l&15)][kt*32 + (l>>4)*8 + j]
//   ushort offset = (tile*(K/32) + kt)*512 + l*8
// Layer-1 LDS operand additionally slot-swizzled: phys_slot = l ^ (kt<<1)
// (makes both the gather's direct stores and the MFMA reads bank-optimal).

// ---------------- bucketA: LDS counting sort -> coalesced bucket writes ---------
__global__ __launch_bounds__(256) void bucketA_kernel(
    const int* __restrict__ src, const int* __restrict__ dst,
    int* __restrict__ gCursD, int* __restrict__ gCursS,
    uint* __restrict__ pairsD, ushort* __restrict__ srcB, int E)
{
    __shared__ ushort sE[2048], dE[2048];      // 8 KB
    __shared__ uint   sortD[2048];             // 8 KB
    __shared__ ushort sortS[2048];             // 4 KB
    __shared__ int cntD[256], cntS[256];
    __shared__ int offD[256], offS[256];
    __shared__ int curD[256], curS[256];
    __shared__ int gBaseD[256], gBaseS[256];
    __shared__ int sd[256];

    const int tid = threadIdx.x;
    const int e0  = blockIdx.x * 2048;
    const int nE  = min(2048, E - e0);

    cntD[tid] = 0; cntS[tid] = 0;
    __syncthreads();
    #pragma unroll
    for (int q = 0; q < 8; ++q) {
        int i = q * 256 + tid;
        if (i < nE) {
            int s = src[e0 + i], d = dst[e0 + i];   // < 65536: fit ushort
            sE[i] = (ushort)s;
            dE[i] = (ushort)d;
            atomicAdd(&cntD[d >> 8], 1);
            atomicAdd(&cntS[s >> 8], 1);
        }
    }
    __syncthreads();

    int ownD = cntD[tid];
    sd[tid] = ownD;
    __syncthreads();
    #pragma unroll
    for (int off = 1; off < 256; off <<= 1) {
        int t = (tid >= off) ? sd[tid - off] : 0;
        __syncthreads();
        sd[tid] += t;
        __syncthreads();
    }
    offD[tid] = sd[tid] - ownD;
    __syncthreads();

    int ownS = cntS[tid];
    sd[tid] = ownS;
    __syncthreads();
    #pragma unroll
    for (int off = 1; off < 256; off <<= 1) {
        int t = (tid >= off) ? sd[tid - off] : 0;
        __syncthreads();
        sd[tid] += t;
        __syncthreads();
    }
    offS[tid] = sd[tid] - ownS;

    curD[tid] = offD[tid];
    curS[tid] = offS[tid];
    if (tid < NBUCK) {
        gBaseD[tid] = tid * BCAP + atomicAdd(&gCursD[tid], cntD[tid]);
        gBaseS[tid] = tid * BCAP + atomicAdd(&gCursS[tid], cntS[tid]);
    }
    __syncthreads();

    #pragma unroll
    for (int q = 0; q < 8; ++q) {
        int i = q * 256 + tid;
        if (i < nE) {
            int s = sE[i], d = dE[i];
            int slot  = atomicAdd(&curD[d >> 8], 1);
            sortD[slot] = ((uint)s << 16) | (uint)d;
            int slot2 = atomicAdd(&curS[s >> 8], 1);
            sortS[slot2] = (ushort)s;
        }
    }
    __syncthreads();

    #pragma unroll
    for (int q = 0; q < 8; ++q) {
        int i = q * 256 + tid;
        if (i < nE) {
            uint v = sortD[i];
            int s = (int)(v >> 16), d = (int)(v & 0xFFFFu);
            int b = d >> 8;
            int gpos = gBaseD[b] + (i - offD[b]);
            if (gpos < (b + 1) * BCAP)
                pairsD[gpos] = ((uint)s << 8) | (uint)(d & 255);
            int sv = sortS[i];
            int bs = sv >> 8;
            int gpos2 = gBaseS[bs] + (i - offS[bs]);
            if (gpos2 < (bs + 1) * BCAP)
                srcB[gpos2] = (ushort)(sv & 255);
        }
    }
}

// ---------------- bucketB: 3 roles in one grid (512 threads/block) --------------
// [0,196): per-bucket fine CSR -> edge_srcF (ushort src, node-sorted).
// [196,392): src histogram -> pre-scaled fp16 featsH for the bucket's nodes.
// [392,432): weight conversion -> frag-major single-plane fp16 Wfc/Wf1/Wf2.
__global__ __launch_bounds__(512) void bucketB_kernel(
    const uint* __restrict__ pairsD, const ushort* __restrict__ srcB,
    const int* __restrict__ gCursD, const int* __restrict__ gCursS,
    ushort* __restrict__ edge_srcF, int2* __restrict__ begcnt,
    const float* __restrict__ feats, _Float16* __restrict__ featsH,
    const float* __restrict__ Wc, const float* __restrict__ W1,
    const float* __restrict__ W2, ushort* __restrict__ Wfc,
    ushort* __restrict__ Wf1, ushort* __restrict__ Wf2)
{
    __shared__ uint pE[BCAP];                     // 18.4 KB
    __shared__ int h[256], sd[256], curs[256];
    __shared__ float scs[256];
    const int tid = threadIdx.x;

    if (blockIdx.x < NBUCK) {
        const int b = blockIdx.x;
        const int base = b * BCAP;
        const int cnt  = min(gCursD[b], BCAP);
        if (tid < 256) h[tid] = 0;
        __syncthreads();
        for (int i = tid; i < cnt; i += 512) {
            uint p = pairsD[base + i];
            pE[i] = p;
            atomicAdd(&h[p & 255], 1);
        }
        __syncthreads();
        int myc = (tid < 256) ? h[tid] : 0;
        if (tid < 256) sd[tid] = myc;
        __syncthreads();
        #pragma unroll
        for (int off = 1; off < 256; off <<= 1) {
            int t = (tid >= off && tid < 256) ? sd[tid - off] : 0;
            __syncthreads();
            if (tid < 256) sd[tid] += t;
            __syncthreads();
        }
        if (tid < 256) {
            int excl = sd[tid] - myc;
            int n = b * 256 + tid;
            if (n < N_NODES) begcnt[n] = make_int2(base + excl, myc);
            curs[tid] = excl;
        }
        __syncthreads();
        for (int i = tid; i < cnt; i += 512) {
            uint p = pE[i];
            int slot = atomicAdd(&curs[p & 255], 1);
            edge_srcF[base + slot] = (ushort)(p >> 8);
        }
    } else if (blockIdx.x < 2 * NBUCK) {
        const int b = blockIdx.x - NBUCK;
        const int base = b * BCAP;
        const int cntS = min(gCursS[b], BCAP);
        if (tid < 256) h[tid] = 0;
        __syncthreads();
        for (int i = tid; i < cntS; i += 512)
            atomicAdd(&h[srcB[base + i]], 1);
        __syncthreads();
        if (tid < 256) scs[tid] = rsqrtf(fmaxf((float)h[tid], 1.0f));
        __syncthreads();
        // convert this bucket's 256 nodes: 256 nodes x 16 half8-chunks
        #pragma unroll
        for (int it = 0; it < 8; ++it) {
            int idx = it * 512 + tid;          // (nl<<4)|c8
            int nl = idx >> 4, c8 = idx & 15;
            int n = b * 256 + nl;
            if (n < N_NODES) {
                float sc = scs[nl];
                const float* fp = feats + (size_t)n * IN_DIM + c8 * 8;
                float4 v0 = *reinterpret_cast<const float4*>(fp);
                float4 v1 = *reinterpret_cast<const float4*>(fp + 4);
                half8 hv;
                hv[0] = (_Float16)(v0.x * sc); hv[1] = (_Float16)(v0.y * sc);
                hv[2] = (_Float16)(v0.z * sc); hv[3] = (_Float16)(v0.w * sc);
                hv[4] = (_Float16)(v1.x * sc); hv[5] = (_Float16)(v1.y * sc);
                hv[6] = (_Float16)(v1.z * sc); hv[7] = (_Float16)(v1.w * sc);
                *reinterpret_cast<half8*>(&featsH[(size_t)n * IN_DIM + c8 * 8]) = hv;
            }
        }
    } else {
        int idx = (blockIdx.x - 2 * NBUCK) * 512 + tid;   // 40 blocks x 512 = 20480
        const float* W; ushort* Wf; int K, off;
        if (idx < 4096)        { W = Wc; Wf = Wfc; K = 128; off = idx; }
        else if (idx < 12288)  { W = W1; Wf = Wf1; K = 256; off = idx - 4096; }
        else if (idx < 20480)  { W = W2; Wf = Wf2; K = 256; off = idx - 12288; }
        else return;
        int NK = K / 32;
        int l = off & 63;
        int kt = (K == 128) ? ((off >> 6) & 3) : ((off >> 6) & 7);
        int ct = (K == 128) ? (off >> 8) : (off >> 9);
        int col = ct * 16 + (l & 15);
        int kb  = kt * 32 + (l >> 4) * 8;
        half8 hv;
        #pragma unroll
        for (int q = 0; q < 8; ++q)
            hv[q] = (_Float16)W[(size_t)(kb + q) * 256 + col];
        *reinterpret_cast<half8*>(Wf + ((size_t)(ct * NK + kt)) * 512 + l * 8) = hv;
    }
}

// ---------------- fully fused: fp16 gather (unroll 8) + fp16 MFMA MLP -----------
template <int NK>
__device__ __forceinline__ void mfma_loop(
    const ushort* __restrict__ a0, const ushort* __restrict__ a1,
    const ushort* __restrict__ w0, const ushort* __restrict__ w1,
    const ushort* __restrict__ w2, const ushort* __restrict__ w3,
    f32x4 acc[2][4])
{
    #pragma unroll
    for (int kt = 0; kt < NK; ++kt) {
        const int o = kt * 512;
        half8 ah[2], bw[4];
        ah[0] = *reinterpret_cast<const half8*>(a0 + o);
        ah[1] = *reinterpret_cast<const half8*>(a1 + o);
        bw[0] = *reinterpret_cast<const half8*>(w0 + o);
        bw[1] = *reinterpret_cast<const half8*>(w1 + o);
        bw[2] = *reinterpret_cast<const half8*>(w2 + o);
        bw[3] = *reinterpret_cast<const half8*>(w3 + o);
        #pragma unroll
        for (int m = 0; m < 2; ++m) {
            #pragma unroll
            for (int n = 0; n < 4; ++n) {
                acc[m][n] = __builtin_amdgcn_mfma_f32_16x16x32_f16(ah[m], bw[n], acc[m][n], 0, 0, 0);
            }
        }
    }
}

__global__ __launch_bounds__(256, 6) void fused_all_kernel(
    const _Float16* __restrict__ featsH, const ushort* __restrict__ edge_srcF,
    const int2* __restrict__ begcnt,
    const ushort* __restrict__ Wfc, const ushort* __restrict__ Wf1,
    const ushort* __restrict__ Wf2, const float* __restrict__ bc,
    const float* __restrict__ b1, const float* __restrict__ b2,
    float* __restrict__ out, int M)
{
    // ushorts [0,4096): layer-1 A operand (2 tiles x 4 kt chunks, slot-swizzled)
    // after layer 1:   [0,8192) = layer-2/3 A operand (2 tiles x 8 kt)
    __shared__ ushort fb[8192];   // exactly 16 KB

    const int tid  = threadIdx.x;
    const int lane = tid & 63;
    const int wv   = tid >> 6;
    const int blk  = blockIdx.x;
    const int row0 = blk * 32;
    const int fr   = lane & 15;
    const int lg   = lane >> 4;
    const int fh   = fr >> 3;

    // ---- phase A: fp16 gather, 8-edge unroll (8 loads in flight per thread) ----
    {
        const int g   = tid >> 4;     // node-in-half 0..15
        const int l16 = tid & 15;     // owns cols l16*8 .. +7
        const int ktA = l16 >> 2;     // chunk within K=128
        const int seg = l16 & 3;      // 8-col segment within chunk
        #pragma unroll
        for (int p = 0; p < 2; ++p) {
            int nl = p * 16 + g;
            int n  = row0 + nl;
            f32x4 a0 = {0.f, 0.f, 0.f, 0.f}, a1 = {0.f, 0.f, 0.f, 0.f};
            if (n < M) {
                int2 bcn = begcnt[n];
                int j = bcn.x, jend = bcn.x + bcn.y;
                for (; j + 7 < jend; j += 8) {
                    int s0 = edge_srcF[j],     s1 = edge_srcF[j + 1];
                    int s2 = edge_srcF[j + 2], s3 = edge_srcF[j + 3];
                    int s4 = edge_srcF[j + 4], s5 = edge_srcF[j + 5];
                    int s6 = edge_srcF[j + 6], s7 = edge_srcF[j + 7];
                    half8 h0 = *reinterpret_cast<const half8*>(&featsH[(size_t)s0 * IN_DIM + l16 * 8]);
                    half8 h1 = *reinterpret_cast<const half8*>(&featsH[(size_t)s1 * IN_DIM + l16 * 8]);
                    half8 h2 = *reinterpret_cast<const half8*>(&featsH[(size_t)s2 * IN_DIM + l16 * 8]);
                    half8 h3 = *reinterpret_cast<const half8*>(&featsH[(size_t)s3 * IN_DIM + l16 * 8]);
                    half8 h4 = *reinterpret_cast<const half8*>(&featsH[(size_t)s4 * IN_DIM + l16 * 8]);
                    half8 h5 = *reinterpret_cast<const half8*>(&featsH[(size_t)s5 * IN_DIM + l16 * 8]);
                    half8 h6 = *reinterpret_cast<const half8*>(&featsH[(size_t)s6 * IN_DIM + l16 * 8]);
                    half8 h7 = *reinterpret_cast<const half8*>(&featsH[(size_t)s7 * IN_DIM + l16 * 8]);
                    half8 hs = ((h0 + h1) + (h2 + h3)) + ((h4 + h5) + (h6 + h7));
                    a0[0] += (float)hs[0]; a0[1] += (float)hs[1];
                    a0[2] += (float)hs[2]; a0[3] += (float)hs[3];
                    a1[0] += (float)hs[4]; a1[1] += (float)hs[5];
                    a1[2] += (float)hs[6]; a1[3] += (float)hs[7];
                }
                if (j + 3 < jend) {
                    int s0 = edge_srcF[j],     s1 = edge_srcF[j + 1];
                    int s2 = edge_srcF[j + 2], s3 = edge_srcF[j + 3];
                    half8 h0 = *reinterpret_cast<const half8*>(&featsH[(size_t)s0 * IN_DIM + l16 * 8]);
                    half8 h1 = *reinterpret_cast<const half8*>(&featsH[(size_t)s1 * IN_DIM + l16 * 8]);
                    half8 h2 = *reinterpret_cast<const half8*>(&featsH[(size_t)s2 * IN_DIM + l16 * 8]);
                    half8 h3 = *reinterpret_cast<const half8*>(&featsH[(size_t)s3 * IN_DIM + l16 * 8]);
                    half8 hs = (h0 + h1) + (h2 + h3);
                    a0[0] += (float)hs[0]; a0[1] += (float)hs[1];
                    a0[2] += (float)hs[2]; a0[3] += (float)hs[3];
                    a1[0] += (float)hs[4]; a1[1] += (float)hs[5];
                    a1[2] += (float)hs[6]; a1[3] += (float)hs[7];
                    j += 4;
                }
                for (; j < jend; ++j) {
                    int s0 = edge_srcF[j];
                    half8 h0 = *reinterpret_cast<const half8*>(&featsH[(size_t)s0 * IN_DIM + l16 * 8]);
                    a0[0] += (float)h0[0]; a0[1] += (float)h0[1];
                    a0[2] += (float)h0[2]; a0[3] += (float)h0[3];
                    a1[0] += (float)h0[4]; a1[1] += (float)h0[5];
                    a1[2] += (float)h0[6]; a1[3] += (float)h0[7];
                }
                float di = rsqrtf(fmaxf((float)bcn.y, 1.0f));
                a0 = a0 * di;
                a1 = a1 * di;
            }
            // direct frag-major fp16 store, slot-swizzled: l' = l ^ (ktA<<1)
            half8 hv;
            #pragma unroll
            for (int q = 0; q < 4; ++q) { hv[q] = (_Float16)a0[q]; hv[4 + q] = (_Float16)a1[q]; }
            const int tile = nl >> 4;                       // == p
            const int l    = seg * 16 + (nl & 15);
            const int lsw_ = l ^ (ktA << 1);
            *reinterpret_cast<half8*>(fb + (tile * 4 + ktA) * 512 + lsw_ * 8) = hv;
        }
    }
    __syncthreads();

    // swizzled per-thread write base for layer-1/2 epilogues (single plane)
    ushort* fbase = fb + wv * 1024 + (lg << 5) + (fr & 7);
    const int lsw = (lane * 8) ^ ((lane >> 4) << 3);

    f32x4 acc[2][4];

    // ---- layer 1: K=128 (NK=4), A from fb (slot-swizzled per kt) ----
    {
        const ushort* w0 = Wfc + ((size_t)(wv * 4 + 0) * 4) * 512 + lane * 8;
        const ushort* w1 = Wfc + ((size_t)(wv * 4 + 1) * 4) * 512 + lane * 8;
        const ushort* w2 = Wfc + ((size_t)(wv * 4 + 2) * 4) * 512 + lane * 8;
        const ushort* w3 = Wfc + ((size_t)(wv * 4 + 3) * 4) * 512 + lane * 8;
        #pragma unroll
        for (int m = 0; m < 2; ++m)
            #pragma unroll
            for (int n = 0; n < 4; ++n) acc[m][n] = (f32x4)(0.f);
        const int la8 = lane * 8;
        __builtin_amdgcn_s_setprio(1);
        #pragma unroll
        for (int kt = 0; kt < 4; ++kt) {
            const int ao = kt * 512 + (la8 ^ (kt << 4));   // (lane ^ (kt<<1)) * 8
            const int wo = kt * 512;
            half8 ah[2], bw[4];
            ah[0] = *reinterpret_cast<const half8*>(fb + ao);
            ah[1] = *reinterpret_cast<const half8*>(fb + 2048 + ao);
            bw[0] = *reinterpret_cast<const half8*>(w0 + wo);
            bw[1] = *reinterpret_cast<const half8*>(w1 + wo);
            bw[2] = *reinterpret_cast<const half8*>(w2 + wo);
            bw[3] = *reinterpret_cast<const half8*>(w3 + wo);
            #pragma unroll
            for (int m = 0; m < 2; ++m)
                #pragma unroll
                for (int n = 0; n < 4; ++n)
                    acc[m][n] = __builtin_amdgcn_mfma_f32_16x16x32_f16(ah[m], bw[n], acc[m][n], 0, 0, 0);
        }
        __builtin_amdgcn_s_setprio(0);
    }
    __syncthreads();   // all layer-1 A reads done before epilogue overwrites

    // layer-1 epilogue: silu -> fp16 -> fb (swizzled direct, single plane)
    #pragma unroll
    for (int n = 0; n < 4; ++n) {
        float b = bc[wv * 64 + n * 16 + fr];
        const int kseg = 2 * (n & 1) + fh;
        const int noff = (n >> 1) * 512 + kseg * 128;
        #pragma unroll
        for (int m = 0; m < 2; ++m) {
            f32x4 v = acc[m][n];
            #pragma unroll
            for (int q = 0; q < 4; ++q) {
                _Float16 s = (_Float16)silu_fast(v[q] + b);
                fbase[m * 4096 + noff + (q ^ kseg) * 8] = __builtin_bit_cast(unsigned short, s);
            }
        }
    }
    __syncthreads();

    // ---- layer 2: K=256 (NK=8), A from fb (swizzled) ----
    {
        const ushort* a0 = fb + lsw;
        const ushort* a1 = fb + 4096 + lsw;
        const ushort* w0 = Wf1 + ((size_t)(wv * 4 + 0) * 8) * 512 + lane * 8;
        const ushort* w1 = Wf1 + ((size_t)(wv * 4 + 1) * 8) * 512 + lane * 8;
        const ushort* w2 = Wf1 + ((size_t)(wv * 4 + 2) * 8) * 512 + lane * 8;
        const ushort* w3 = Wf1 + ((size_t)(wv * 4 + 3) * 8) * 512 + lane * 8;
        #pragma unroll
        for (int m = 0; m < 2; ++m)
            #pragma unroll
            for (int n = 0; n < 4; ++n) acc[m][n] = (f32x4)(0.f);
        __builtin_amdgcn_s_setprio(1);
        mfma_loop<8>(a0, a1, w0, w1, w2, w3, acc);
        __builtin_amdgcn_s_setprio(0);
    }
    __syncthreads();   // all fb reads done before overwrite

    // layer-2 epilogue -> fb (swizzled direct, single plane)
    #pragma unroll
    for (int n = 0; n < 4; ++n) {
        float b = b1[wv * 64 + n * 16 + fr];
        const int kseg = 2 * (n & 1) + fh;
        const int noff = (n >> 1) * 512 + kseg * 128;
        #pragma unroll
        for (int m = 0; m < 2; ++m) {
            f32x4 v = acc[m][n];
            #pragma unroll
            for (int q = 0; q < 4; ++q) {
                _Float16 s = (_Float16)silu_fast(v[q] + b);
                fbase[m * 4096 + noff + (q ^ kseg) * 8] = __builtin_bit_cast(unsigned short, s);
            }
        }
    }
    __syncthreads();

    // ---- layer 3: K=256 (NK=8), A from fb (swizzled) ----
    {
        const ushort* a0 = fb + lsw;
        const ushort* a1 = fb + 4096 + lsw;
        const ushort* w0 = Wf2 + ((size_t)(wv * 4 + 0) * 8) * 512 + lane * 8;
        const ushort* w1 = Wf2 + ((size_t)(wv * 4 + 1) * 8) * 512 + lane * 8;
        const ushort* w2 = Wf2 + ((size_t)(wv * 4 + 2) * 8) * 512 + lane * 8;
        const ushort* w3 = Wf2 + ((size_t)(wv * 4 + 3) * 8) * 512 + lane * 8;
        #pragma unroll
        for (int m = 0; m < 2; ++m)
            #pragma unroll
            for (int n = 0; n < 4; ++n) acc[m][n] = (f32x4)(0.f);
        __builtin_amdgcn_s_setprio(1);
        mfma_loop<8>(a0, a1, w0, w1, w2, w3, acc);
        __builtin_amdgcn_s_setprio(0);
    }

    // layer-3 epilogue: direct f32 global stores (64B-contiguous per 16 lanes)
    #pragma unroll
    for (int n = 0; n < 4; ++n) {
        int col = wv * 64 + n * 16 + fr;
        float b = b2[col];
        #pragma unroll
        for (int m = 0; m < 2; ++m) {
            int rowb = row0 + m * 16 + lg * 4;
            f32x4 v = acc[m][n];
            #pragma unroll
            for (int q = 0; q < 4; ++q) {
                int row = rowb + q;
                if (row < M)
                    out[(size_t)row * OUT_DIM + col] = silu_fast(v[q] + b);
            }
        }
    }
}

extern "C" void kernel_launch(void* const* d_in, const int* in_sizes, int n_in,
                              void* d_out, int out_size, void* d_ws, size_t ws_size,
                              hipStream_t stream)
{
    const float* feats  = (const float*)d_in[0];
    const float* W_conv = (const float*)d_in[1];
    const float* b_conv = (const float*)d_in[2];
    const float* W1     = (const float*)d_in[3];
    const float* b1     = (const float*)d_in[4];
    const float* W2     = (const float*)d_in[5];
    const float* b2     = (const float*)d_in[6];
    const int*   src    = (const int*)d_in[7];
    const int*   dst    = (const int*)d_in[8];

    // workspace layout (bytes):
    //   [0, 784)                 gCursD (196 ints)
    //   [1024, 1808)             gCursS
    //   [4096, 404,096)          begcnt (50000 int2)
    //   [1,000,000, 4,612,672)   pairsD  (196 x 4608 uint)
    //   [4,612,672, 6,419,008)   srcB    (196 x 4608 ushort)
    //   [6,420,480, 8,226,816)   edge_srcF (196 x 4608 ushort, node-sorted CSR)
    //   [10,000,000, 22,800,000) featsH (50000 x 128 fp16, pre-scaled)
    //   [80,600,064, 80,665,600) Wfc (fp16 frag-major, 64KB)
    //   [80,665,600, 80,796,672) Wf1 (128KB)
    //   [80,796,672, 80,927,744) Wf2 (128KB)
    char* ws = (char*)d_ws;
    int*    gCursD    = (int*)(ws + 0);
    int*    gCursS    = (int*)(ws + 1024);
    int2*   begcnt    = (int2*)(ws + 4096);
    uint*   pairsD    = (uint*)(ws + 1000000);
    ushort* srcB      = (ushort*)(ws + 4612672);
    ushort* edge_srcF = (ushort*)(ws + 6420480);
    _Float16* featsH  = (_Float16*)(ws + 10000000);
    ushort* Wfc       = (ushort*)(ws + 80600064);
    ushort* Wf1       = (ushort*)(ws + 80665600);
    ushort* Wf2       = (ushort*)(ws + 80796672);

    hipMemsetAsync(ws, 0, 2048, stream);   // zero gCursD + gCursS

    const int ablocks = (N_EDGES + 2047) / 2048;   // 391
    bucketA_kernel<<<ablocks, 256, 0, stream>>>(src, dst, gCursD, gCursS, pairsD, srcB, N_EDGES);
    bucketB_kernel<<<NBUCK * 2 + 40, 512, 0, stream>>>(pairsD, srcB, gCursD, gCursS,
                                                       edge_srcF, begcnt,
                                                       feats, featsH,
                                                       W_conv, W1, W2, Wfc, Wf1, Wf2);

    const int gblocks = (N_NODES + 31) / 32;   // 1563
    fused_all_kernel<<<gblocks, 256, 0, stream>>>(featsH, edge_srcF, begcnt,
                                                  Wfc, Wf1, Wf2, b_conv, b1, b2,
                                                  (float*)d_out, N_NODES);
}

// Round 29
// 106.147 us; speedup vs baseline: 1.1162x; 1.0005x over previous
//
#include <hip/hip_runtime.h>
#include <hip/hip_bf16.h>

#define N_NODES 50000
#define N_EDGES 800000
#define IN_DIM  128
#define OUT_DIM 256
#define NBUCK   196        // ceil(50000/256) coarse buckets (256 nodes each)
#define BCAP    4608       // per-bucket edge capacity: mean 4096 + 8 sigma

typedef float f32x4 __attribute__((ext_vector_type(4)));
typedef _Float16 half8 __attribute__((ext_vector_type(8)));

__device__ __forceinline__ float silu_fast(float x) {
    return x * __builtin_amdgcn_rcpf(1.0f + __expf(-x));
}

// ======== frag-major layout (single fp16 plane) ========
// Operand X (row-major logical [R][K]) stored as 1KB chunks of half8:
//   chunk(tile, kt, lane l) = fp16[8] of X[tile*16 + (l&15)][kt*32 + (l>>4)*8 + j]
//   ushort offset = (tile*(K/32) + kt)*512 + l*8
// Layer-1 LDS operand additionally slot-swizzled: phys_slot = l ^ (kt<<1).

// ---------------- bucketA: LDS counting sort -> coalesced bucket writes ---------
// Scans via wave shuffle (1 barrier each instead of 16); D and S scans run in
// parallel in registers sharing the same barrier.
__global__ __launch_bounds__(256) void bucketA_kernel(
    const int* __restrict__ src, const int* __restrict__ dst,
    int* __restrict__ gCursD, int* __restrict__ gCursS,
    uint* __restrict__ pairsD, ushort* __restrict__ srcB, int E)
{
    __shared__ ushort sE[2048], dE[2048];      // 8 KB
    __shared__ uint   sortD[2048];             // 8 KB
    __shared__ ushort sortS[2048];             // 4 KB
    __shared__ int cntD[256], cntS[256];
    __shared__ int offD[256], offS[256];
    __shared__ int curD[256], curS[256];
    __shared__ int gBaseD[256], gBaseS[256];
    __shared__ int wtD[4], wtS[4];

    const int tid = threadIdx.x;
    const int ln  = tid & 63;
    const int wv_ = tid >> 6;
    const int e0  = blockIdx.x * 2048;
    const int nE  = min(2048, E - e0);

    cntD[tid] = 0; cntS[tid] = 0;
    __syncthreads();
    #pragma unroll
    for (int q = 0; q < 8; ++q) {
        int i = q * 256 + tid;
        if (i < nE) {
            int s = src[e0 + i], d = dst[e0 + i];   // < 65536: fit ushort
            sE[i] = (ushort)s;
            dE[i] = (ushort)d;
            atomicAdd(&cntD[d >> 8], 1);
            atomicAdd(&cntS[s >> 8], 1);
        }
    }
    __syncthreads();

    // dual wave-shuffle inclusive scans (D and S in parallel)
    int ownD = cntD[tid], ownS = cntS[tid];
    int incD = ownD, incS = ownS;
    #pragma unroll
    for (int o = 1; o < 64; o <<= 1) {
        int tD = __shfl_up(incD, o);
        int tS = __shfl_up(incS, o);
        if (ln >= o) { incD += tD; incS += tS; }
    }
    if (ln == 63) { wtD[wv_] = incD; wtS[wv_] = incS; }
    __syncthreads();
    int preD = 0, preS = 0;
    #pragma unroll
    for (int w = 0; w < 4; ++w) {
        if (w < wv_) { preD += wtD[w]; preS += wtS[w]; }
    }
    offD[tid] = preD + incD - ownD;
    offS[tid] = preS + incS - ownS;

    curD[tid] = offD[tid];
    curS[tid] = offS[tid];
    if (tid < NBUCK) {
        gBaseD[tid] = tid * BCAP + atomicAdd(&gCursD[tid], ownD);
        gBaseS[tid] = tid * BCAP + atomicAdd(&gCursS[tid], ownS);
    }
    __syncthreads();

    #pragma unroll
    for (int q = 0; q < 8; ++q) {
        int i = q * 256 + tid;
        if (i < nE) {
            int s = sE[i], d = dE[i];
            int slot  = atomicAdd(&curD[d >> 8], 1);
            sortD[slot] = ((uint)s << 16) | (uint)d;
            int slot2 = atomicAdd(&curS[s >> 8], 1);
            sortS[slot2] = (ushort)s;
        }
    }
    __syncthreads();

    #pragma unroll
    for (int q = 0; q < 8; ++q) {
        int i = q * 256 + tid;
        if (i < nE) {
            uint v = sortD[i];
            int s = (int)(v >> 16), d = (int)(v & 0xFFFFu);
            int b = d >> 8;
            int gpos = gBaseD[b] + (i - offD[b]);
            if (gpos < (b + 1) * BCAP)
                pairsD[gpos] = ((uint)s << 8) | (uint)(d & 255);
            int sv = sortS[i];
            int bs = sv >> 8;
            int gpos2 = gBaseS[bs] + (i - offS[bs]);
            if (gpos2 < (bs + 1) * BCAP)
                srcB[gpos2] = (ushort)(sv & 255);
        }
    }
}

// ---------------- bucketB: 3 roles in one grid (512 threads/block) --------------
// [0,196): per-bucket fine CSR -> edge_srcF (ushort src, node-sorted);
//          scan via wave shuffle (1 barrier).
// [196,392): src histogram -> pre-scaled fp16 featsH for the bucket's nodes.
// [392,432): weight conversion -> frag-major single-plane fp16 Wfc/Wf1/Wf2.
__global__ __launch_bounds__(512) void bucketB_kernel(
    const uint* __restrict__ pairsD, const ushort* __restrict__ srcB,
    const int* __restrict__ gCursD, const int* __restrict__ gCursS,
    ushort* __restrict__ edge_srcF, int2* __restrict__ begcnt,
    const float* __restrict__ feats, _Float16* __restrict__ featsH,
    const float* __restrict__ Wc, const float* __restrict__ W1,
    const float* __restrict__ W2, ushort* __restrict__ Wfc,
    ushort* __restrict__ Wf1, ushort* __restrict__ Wf2)
{
    __shared__ uint pE[BCAP];                     // 18.4 KB
    __shared__ int h[256], curs[256];
    __shared__ int wt[4];
    __shared__ float scs[256];
    const int tid = threadIdx.x;
    const int ln  = tid & 63;

    if (blockIdx.x < NBUCK) {
        const int b = blockIdx.x;
        const int base = b * BCAP;
        const int cnt  = min(gCursD[b], BCAP);
        if (tid < 256) h[tid] = 0;
        __syncthreads();
        for (int i = tid; i < cnt; i += 512) {
            uint p = pairsD[base + i];
            pE[i] = p;
            atomicAdd(&h[p & 255], 1);
        }
        __syncthreads();
        // wave-shuffle scan over the first 256 counters (waves 0..3)
        int myc = (tid < 256) ? h[tid] : 0;
        int inc = myc;
        #pragma unroll
        for (int o = 1; o < 64; o <<= 1) {
            int t = __shfl_up(inc, o);
            if (ln >= o) inc += t;
        }
        if (tid < 256 && ln == 63) wt[tid >> 6] = inc;
        __syncthreads();
        if (tid < 256) {
            int pre = 0;
            #pragma unroll
            for (int w = 0; w < 4; ++w)
                if (w < (tid >> 6)) pre += wt[w];
            int excl = pre + inc - myc;
            int n = b * 256 + tid;
            if (n < N_NODES) begcnt[n] = make_int2(base + excl, myc);
            curs[tid] = excl;
        }
        __syncthreads();
        for (int i = tid; i < cnt; i += 512) {
            uint p = pE[i];
            int slot = atomicAdd(&curs[p & 255], 1);
            edge_srcF[base + slot] = (ushort)(p >> 8);
        }
    } else if (blockIdx.x < 2 * NBUCK) {
        const int b = blockIdx.x - NBUCK;
        const int base = b * BCAP;
        const int cntS = min(gCursS[b], BCAP);
        if (tid < 256) h[tid] = 0;
        __syncthreads();
        for (int i = tid; i < cntS; i += 512)
            atomicAdd(&h[srcB[base + i]], 1);
        __syncthreads();
        if (tid < 256) scs[tid] = rsqrtf(fmaxf((float)h[tid], 1.0f));
        __syncthreads();
        // convert this bucket's 256 nodes: 256 nodes x 16 half8-chunks
        #pragma unroll
        for (int it = 0; it < 8; ++it) {
            int idx = it * 512 + tid;          // (nl<<4)|c8
            int nl = idx >> 4, c8 = idx & 15;
            int n = b * 256 + nl;
            if (n < N_NODES) {
                float sc = scs[nl];
                const float* fp = feats + (size_t)n * IN_DIM + c8 * 8;
                float4 v0 = *reinterpret_cast<const float4*>(fp);
                float4 v1 = *reinterpret_cast<const float4*>(fp + 4);
                half8 hv;
                hv[0] = (_Float16)(v0.x * sc); hv[1] = (_Float16)(v0.y * sc);
                hv[2] = (_Float16)(v0.z * sc); hv[3] = (_Float16)(v0.w * sc);
                hv[4] = (_Float16)(v1.x * sc); hv[5] = (_Float16)(v1.y * sc);
                hv[6] = (_Float16)(v1.z * sc); hv[7] = (_Float16)(v1.w * sc);
                *reinterpret_cast<half8*>(&featsH[(size_t)n * IN_DIM + c8 * 8]) = hv;
            }
        }
    } else {
        int idx = (blockIdx.x - 2 * NBUCK) * 512 + tid;   // 40 blocks x 512 = 20480
        const float* W; ushort* Wf; int K, off;
        if (idx < 4096)        { W = Wc; Wf = Wfc; K = 128; off = idx; }
        else if (idx < 12288)  { W = W1; Wf = Wf1; K = 256; off = idx - 4096; }
        else if (idx < 20480)  { W = W2; Wf = Wf2; K = 256; off = idx - 12288; }
        else return;
        int NK = K / 32;
        int l = off & 63;
        int kt = (K == 128) ? ((off >> 6) & 3) : ((off >> 6) & 7);
        int ct = (K == 128) ? (off >> 8) : (off >> 9);
        int col = ct * 16 + (l & 15);
        int kb  = kt * 32 + (l >> 4) * 8;
        half8 hv;
        #pragma unroll
        for (int q = 0; q < 8; ++q)
            hv[q] = (_Float16)W[(size_t)(kb + q) * 256 + col];
        *reinterpret_cast<half8*>(Wf + ((size_t)(ct * NK + kt)) * 512 + l * 8) = hv;
    }
}

// ---------------- fully fused: fp16 gather (unroll 8) + fp16 MFMA MLP -----------
template <int NK>
__device__ __forceinline__ void mfma_loop(
    const ushort* __restrict__ a0, const ushort* __restrict__ a1,
    const ushort* __restrict__ w0, const ushort* __restrict__ w1,
    const ushort* __restrict__ w2, const ushort* __restrict__ w3,
    f32x4 acc[2][4])
{
    #pragma unroll
    for (int kt = 0; kt < NK; ++kt) {
        const int o = kt * 512;
        half8 ah[2], bw[4];
        ah[0] = *reinterpret_cast<const half8*>(a0 + o);
        ah[1] = *reinterpret_cast<const half8*>(a1 + o);
        bw[0] = *reinterpret_cast<const half8*>(w0 + o);
        bw[1] = *reinterpret_cast<const half8*>(w1 + o);
        bw[2] = *reinterpret_cast<const half8*>(w2 + o);
        bw[3] = *reinterpret_cast<const half8*>(w3 + o);
        #pragma unroll
        for (int m = 0; m < 2; ++m) {
            #pragma unroll
            for (int n = 0; n < 4; ++n) {
                acc[m][n] = __builtin_amdgcn_mfma_f32_16x16x32_f16(ah[m], bw[n], acc[m][n], 0, 0, 0);
            }
        }
    }
}

__global__ __launch_bounds__(256, 6) void fused_all_kernel(
    const _Float16* __restrict__ featsH, const ushort* __restrict__ edge_srcF,
    const int2* __restrict__ begcnt,
    const ushort* __restrict__ Wfc, const ushort* __restrict__ Wf1,
    const ushort* __restrict__ Wf2, const float* __restrict__ bc,
    const float* __restrict__ b1, const float* __restrict__ b2,
    float* __restrict__ out, int M)
{
    // ushorts [0,4096): layer-1 A operand (2 tiles x 4 kt chunks, slot-swizzled)
    // after layer 1:   [0,8192) = layer-2/3 A operand (2 tiles x 8 kt)
    __shared__ ushort fb[8192];   // exactly 16 KB

    const int tid  = threadIdx.x;
    const int lane = tid & 63;
    const int wv   = tid >> 6;
    const int blk  = blockIdx.x;
    const int row0 = blk * 32;
    const int fr   = lane & 15;
    const int lg   = lane >> 4;
    const int fh   = fr >> 3;

    // ---- phase A: fp16 gather, 8-edge unroll (8 loads in flight per thread) ----
    {
        const int g   = tid >> 4;     // node-in-half 0..15
        const int l16 = tid & 15;     // owns cols l16*8 .. +7
        const int ktA = l16 >> 2;     // chunk within K=128
        const int seg = l16 & 3;      // 8-col segment within chunk
        #pragma unroll
        for (int p = 0; p < 2; ++p) {
            int nl = p * 16 + g;
            int n  = row0 + nl;
            f32x4 a0 = {0.f, 0.f, 0.f, 0.f}, a1 = {0.f, 0.f, 0.f, 0.f};
            if (n < M) {
                int2 bcn = begcnt[n];
                int j = bcn.x, jend = bcn.x + bcn.y;
                for (; j + 7 < jend; j += 8) {
                    int s0 = edge_srcF[j],     s1 = edge_srcF[j + 1];
                    int s2 = edge_srcF[j + 2], s3 = edge_srcF[j + 3];
                    int s4 = edge_srcF[j + 4], s5 = edge_srcF[j + 5];
                    int s6 = edge_srcF[j + 6], s7 = edge_srcF[j + 7];
                    half8 h0 = *reinterpret_cast<const half8*>(&featsH[(size_t)s0 * IN_DIM + l16 * 8]);
                    half8 h1 = *reinterpret_cast<const half8*>(&featsH[(size_t)s1 * IN_DIM + l16 * 8]);
                    half8 h2 = *reinterpret_cast<const half8*>(&featsH[(size_t)s2 * IN_DIM + l16 * 8]);
                    half8 h3 = *reinterpret_cast<const half8*>(&featsH[(size_t)s3 * IN_DIM + l16 * 8]);
                    half8 h4 = *reinterpret_cast<const half8*>(&featsH[(size_t)s4 * IN_DIM + l16 * 8]);
                    half8 h5 = *reinterpret_cast<const half8*>(&featsH[(size_t)s5 * IN_DIM + l16 * 8]);
                    half8 h6 = *reinterpret_cast<const half8*>(&featsH[(size_t)s6 * IN_DIM + l16 * 8]);
                    half8 h7 = *reinterpret_cast<const half8*>(&featsH[(size_t)s7 * IN_DIM + l16 * 8]);
                    half8 hs = ((h0 + h1) + (h2 + h3)) + ((h4 + h5) + (h6 + h7));
                    a0[0] += (float)hs[0]; a0[1] += (float)hs[1];
                    a0[2] += (float)hs[2]; a0[3] += (float)hs[3];
                    a1[0] += (float)hs[4]; a1[1] += (float)hs[5];
                    a1[2] += (float)hs[6]; a1[3] += (float)hs[7];
                }
                if (j + 3 < jend) {
                    int s0 = edge_srcF[j],     s1 = edge_srcF[j + 1];
                    int s2 = edge_srcF[j + 2], s3 = edge_srcF[j + 3];
                    half8 h0 = *reinterpret_cast<const half8*>(&featsH[(size_t)s0 * IN_DIM + l16 * 8]);
                    half8 h1 = *reinterpret_cast<const half8*>(&featsH[(size_t)s1 * IN_DIM + l16 * 8]);
                    half8 h2 = *reinterpret_cast<const half8*>(&featsH[(size_t)s2 * IN_DIM + l16 * 8]);
                    half8 h3 = *reinterpret_cast<const half8*>(&featsH[(size_t)s3 * IN_DIM + l16 * 8]);
                    half8 hs = (h0 + h1) + (h2 + h3);
                    a0[0] += (float)hs[0]; a0[1] += (float)hs[1];
                    a0[2] += (float)hs[2]; a0[3] += (float)hs[3];
                    a1[0] += (float)hs[4]; a1[1] += (float)hs[5];
                    a1[2] += (float)hs[6]; a1[3] += (float)hs[7];
                    j += 4;
                }
                for (; j < jend; ++j) {
                    int s0 = edge_srcF[j];
                    half8 h0 = *reinterpret_cast<const half8*>(&featsH[(size_t)s0 * IN_DIM + l16 * 8]);
                    a0[0] += (float)h0[0]; a0[1] += (float)h0[1];
                    a0[2] += (float)h0[2]; a0[3] += (float)h0[3];
                    a1[0] += (float)h0[4]; a1[1] += (float)h0[5];
                    a1[2] += (float)h0[6]; a1[3] += (float)h0[7];
                }
                float di = rsqrtf(fmaxf((float)bcn.y, 1.0f));
                a0 = a0 * di;
                a1 = a1 * di;
            }
            // direct frag-major fp16 store, slot-swizzled: l' = l ^ (ktA<<1)
            half8 hv;
            #pragma unroll
            for (int q = 0; q < 4; ++q) { hv[q] = (_Float16)a0[q]; hv[4 + q] = (_Float16)a1[q]; }
            const int tile = nl >> 4;                       // == p
            const int l    = seg * 16 + (nl & 15);
            const int lsw_ = l ^ (ktA << 1);
            *reinterpret_cast<half8*>(fb + (tile * 4 + ktA) * 512 + lsw_ * 8) = hv;
        }
    }
    __syncthreads();

    // swizzled per-thread write base for layer-1/2 epilogues (single plane)
    ushort* fbase = fb + wv * 1024 + (lg << 5) + (fr & 7);
    const int lsw = (lane * 8) ^ ((lane >> 4) << 3);

    f32x4 acc[2][4];

    // ---- layer 1: K=128 (NK=4), A from fb (slot-swizzled per kt) ----
    {
        const ushort* w0 = Wfc + ((size_t)(wv * 4 + 0) * 4) * 512 + lane * 8;
        const ushort* w1 = Wfc + ((size_t)(wv * 4 + 1) * 4) * 512 + lane * 8;
        const ushort* w2 = Wfc + ((size_t)(wv * 4 + 2) * 4) * 512 + lane * 8;
        const ushort* w3 = Wfc + ((size_t)(wv * 4 + 3) * 4) * 512 + lane * 8;
        #pragma unroll
        for (int m = 0; m < 2; ++m)
            #pragma unroll
            for (int n = 0; n < 4; ++n) acc[m][n] = (f32x4)(0.f);
        const int la8 = lane * 8;
        __builtin_amdgcn_s_setprio(1);
        #pragma unroll
        for (int kt = 0; kt < 4; ++kt) {
            const int ao = kt * 512 + (la8 ^ (kt << 4));   // (lane ^ (kt<<1)) * 8
            const int wo = kt * 512;
            half8 ah[2], bw[4];
            ah[0] = *reinterpret_cast<const half8*>(fb + ao);
            ah[1] = *reinterpret_cast<const half8*>(fb + 2048 + ao);
            bw[0] = *reinterpret_cast<const half8*>(w0 + wo);
            bw[1] = *reinterpret_cast<const half8*>(w1 + wo);
            bw[2] = *reinterpret_cast<const half8*>(w2 + wo);
            bw[3] = *reinterpret_cast<const half8*>(w3 + wo);
            #pragma unroll
            for (int m = 0; m < 2; ++m)
                #pragma unroll
                for (int n = 0; n < 4; ++n)
                    acc[m][n] = __builtin_amdgcn_mfma_f32_16x16x32_f16(ah[m], bw[n], acc[m][n], 0, 0, 0);
        }
        __builtin_amdgcn_s_setprio(0);
    }
    __syncthreads();   // all layer-1 A reads done before epilogue overwrites

    // layer-1 epilogue: silu -> fp16 -> fb (swizzled direct, single plane)
    #pragma unroll
    for (int n = 0; n < 4; ++n) {
        float b = bc[wv * 64 + n * 16 + fr];
        const int kseg = 2 * (n & 1) + fh;
        const int noff = (n >> 1) * 512 + kseg * 128;
        #pragma unroll
        for (int m = 0; m < 2; ++m) {
            f32x4 v = acc[m][n];
            #pragma unroll
            for (int q = 0; q < 4; ++q) {
                _Float16 s = (_Float16)silu_fast(v[q] + b);
                fbase[m * 4096 + noff + (q ^ kseg) * 8] = __builtin_bit_cast(unsigned short, s);
            }
        }
    }
    __syncthreads();

    // ---- layer 2: K=256 (NK=8), A from fb (swizzled) ----
    {
        const ushort* a0 = fb + lsw;
        const ushort* a1 = fb + 4096 + lsw;
        const ushort* w0 = Wf1 + ((size_t)(wv * 4 + 0) * 8) * 512 + lane * 8;
        const ushort* w1 = Wf1 + ((size_t)(wv * 4 + 1) * 8) * 512 + lane * 8;
        const ushort* w2 = Wf1 + ((size_t)(wv * 4 + 2) * 8) * 512 + lane * 8;
        const ushort* w3 = Wf1 + ((size_t)(wv * 4 + 3) * 8) * 512 + lane * 8;
        #pragma unroll
        for (int m = 0; m < 2; ++m)
            #pragma unroll
            for (int n = 0; n < 4; ++n) acc[m][n] = (f32x4)(0.f);
        __builtin_amdgcn_s_setprio(1);
        mfma_loop<8>(a0, a1, w0, w1, w2, w3, acc);
        __builtin_amdgcn_s_setprio(0);
    }
    __syncthreads();   // all fb reads done before overwrite

    // layer-2 epilogue -> fb (swizzled direct, single plane)
    #pragma unroll
    for (int n = 0; n < 4; ++n) {
        float b = b1[wv * 64 + n * 16 + fr];
        const int kseg = 2 * (n & 1) + fh;
        const int noff = (n >> 1) * 512 + kseg * 128;
        #pragma unroll
        for (int m = 0; m < 2; ++m) {
            f32x4 v = acc[m][n];
            #pragma unroll
            for (int q = 0; q < 4; ++q) {
                _Float16 s = (_Float16)silu_fast(v[q] + b);
                fbase[m * 4096 + noff + (q ^ kseg) * 8] = __builtin_bit_cast(unsigned short, s);
            }
        }
    }
    __syncthreads();

    // ---- layer 3: K=256 (NK=8), A from fb (swizzled) ----
    {
        const ushort* a0 = fb + lsw;
        const ushort* a1 = fb + 4096 + lsw;
        const ushort* w0 = Wf2 + ((size_t)(wv * 4 + 0) * 8) * 512 + lane * 8;
        const ushort* w1 = Wf2 + ((size_t)(wv * 4 + 1) * 8) * 512 + lane * 8;
        const ushort* w2 = Wf2 + ((size_t)(wv * 4 + 2) * 8) * 512 + lane * 8;
        const ushort* w3 = Wf2 + ((size_t)(wv * 4 + 3) * 8) * 512 + lane * 8;
        #pragma unroll
        for (int m = 0; m < 2; ++m)
            #pragma unroll
            for (int n = 0; n < 4; ++n) acc[m][n] = (f32x4)(0.f);
        __builtin_amdgcn_s_setprio(1);
        mfma_loop<8>(a0, a1, w0, w1, w2, w3, acc);
        __builtin_amdgcn_s_setprio(0);
    }

    // layer-3 epilogue: direct f32 global stores (64B-contiguous per 16 lanes)
    #pragma unroll
    for (int n = 0; n < 4; ++n) {
        int col = wv * 64 + n * 16 + fr;
        float b = b2[col];
        #pragma unroll
        for (int m = 0; m < 2; ++m) {
            int rowb = row0 + m * 16 + lg * 4;
            f32x4 v = acc[m][n];
            #pragma unroll
            for (int q = 0; q < 4; ++q) {
                int row = rowb + q;
                if (row < M)
                    out[(size_t)row * OUT_DIM + col] = silu_fast(v[q] + b);
            }
        }
    }
}

extern "C" void kernel_launch(void* const* d_in, const int* in_sizes, int n_in,
                              void* d_out, int out_size, void* d_ws, size_t ws_size,
                              hipStream_t stream)
{
    const float* feats  = (const float*)d_in[0];
    const float* W_conv = (const float*)d_in[1];
    const float* b_conv = (const float*)d_in[2];
    const float* W1     = (const float*)d_in[3];
    const float* b1     = (const float*)d_in[4];
    const float* W2     = (const float*)d_in[5];
    const float* b2     = (const float*)d_in[6];
    const int*   src    = (const int*)d_in[7];
    const int*   dst    = (const int*)d_in[8];

    // workspace layout (bytes):
    //   [0, 784)                 gCursD (196 ints)
    //   [1024, 1808)             gCursS
    //   [4096, 404,096)          begcnt (50000 int2)
    //   [1,000,000, 4,612,672)   pairsD  (196 x 4608 uint)
    //   [4,612,672, 6,419,008)   srcB    (196 x 4608 ushort)
    //   [6,420,480, 8,226,816)   edge_srcF (196 x 4608 ushort, node-sorted CSR)
    //   [10,000,000, 22,800,000) featsH (50000 x 128 fp16, pre-scaled)
    //   [80,600,064, 80,665,600) Wfc (fp16 frag-major, 64KB)
    //   [80,665,600, 80,796,672) Wf1 (128KB)
    //   [80,796,672, 80,927,744) Wf2 (128KB)
    char* ws = (char*)d_ws;
    int*    gCursD    = (int*)(ws + 0);
    int*    gCursS    = (int*)(ws + 1024);
    int2*   begcnt    = (int2*)(ws + 4096);
    uint*   pairsD    = (uint*)(ws + 1000000);
    ushort* srcB      = (ushort*)(ws + 4612672);
    ushort* edge_srcF = (ushort*)(ws + 6420480);
    _Float16* featsH  = (_Float16*)(ws + 10000000);
    ushort* Wfc       = (ushort*)(ws + 80600064);
    ushort* Wf1       = (ushort*)(ws + 80665600);
    ushort* Wf2       = (ushort*)(ws + 80796672);

    hipMemsetAsync(ws, 0, 2048, stream);   // zero gCursD + gCursS

    const int ablocks = (N_EDGES + 2047) / 2048;   // 391
    bucketA_kernel<<<ablocks, 256, 0, stream>>>(src, dst, gCursD, gCursS, pairsD, srcB, N_EDGES);
    bucketB_kernel<<<NBUCK * 2 + 40, 512, 0, stream>>>(pairsD, srcB, gCursD, gCursS,
                                                       edge_srcF, begcnt,
                                                       feats, featsH,
                                                       W_conv, W1, W2, Wfc, Wf1, Wf2);

    const int gblocks = (N_NODES + 31) / 32;   // 1563
    fused_all_kernel<<<gblocks, 256, 0, stream>>>(featsH, edge_srcF, begcnt,
                                                  Wfc, Wf1, Wf2, b_conv, b1, b2,
                                                  (float*)d_out, N_NODES);
}